// Round 7
// baseline (283.999 us; speedup 1.0000x reference)
//
#include <hip/hip_runtime.h>
#include <math.h>

typedef unsigned short u16;
typedef __attribute__((ext_vector_type(8))) short short8;
typedef __attribute__((ext_vector_type(4))) float floatx4;

constexpr int BATCH = 16;
constexpr int NI = 1024;
constexpr int CE = 64;
constexpr int CI = 16;
constexpr long long NN2  = (long long)NI * NI;          // 1M
constexpr long long BCN  = (long long)BATCH * CE * NI;  // 1M
constexpr long long BNv  = (long long)BATCH * NI;       // 16K
constexpr long long BNN  = (long long)BATCH * NI * NI;  // 16M
constexpr long long S1 = (long long)CE * NI;            // 65536
constexpr long long S2 = 2 * S1;                        // 131072

__device__ __forceinline__ float lrelu01(float x) { return x > 0.f ? x : 0.01f * x; }

__device__ __forceinline__ u16 f2bf(float f) {
  unsigned u = __builtin_bit_cast(unsigned, f);
  return (u16)((u + 0x7fffu + ((u >> 16) & 1u)) >> 16);  // RNE
}
__device__ __forceinline__ float bf2f(u16 h) {
  unsigned u = ((unsigned)h) << 16;
  return __builtin_bit_cast(float, u);
}
// monotonic uint key for float atomicMax (memset-0 init safe: real-float keys > 0)
__device__ __forceinline__ unsigned fkey(float f) {
  unsigned u = __builtin_bit_cast(unsigned, f);
  return (u & 0x80000000u) ? ~u : (u | 0x80000000u);
}
__device__ __forceinline__ float funkey(unsigned k) {
  unsigned u = (k & 0x80000000u) ? (k & 0x7fffffffu) : ~k;
  return __builtin_bit_cast(float, u);
}
__device__ __forceinline__ float bfsum8(uint4 v, float* out8) {
  out8[0] = bf2f((u16)(v.x & 0xffff)); out8[1] = bf2f((u16)(v.x >> 16));
  out8[2] = bf2f((u16)(v.y & 0xffff)); out8[3] = bf2f((u16)(v.y >> 16));
  out8[4] = bf2f((u16)(v.z & 0xffff)); out8[5] = bf2f((u16)(v.z >> 16));
  out8[6] = bf2f((u16)(v.w & 0xffff)); out8[7] = bf2f((u16)(v.w >> 16));
  return out8[0]+out8[1]+out8[2]+out8[3]+out8[4]+out8[5]+out8[6]+out8[7];
}

// ================= MFMA TN GEMM: C[r][m] = sum_k A[r][k] * Bt[m][k] ==============
// A, Bt bf16 row-major K-contiguous. BK=64, XOR-swizzled 16B chunks in LDS.
// 4 waves 2x2; wave tile (BM/2)x(BN/2); 16x16x32 MFMAs.
// MODE: 2 bf16 +colbias + rowsq atomics | 3 gram exp + rowsum | 4 Abig scatter w/ Z-div |
//       5 fused dual-B + in-staging cc + rank-1 epilogue + LN-stats atomics |
//       6 plain bf16 | 10 A = attention-p on the fly + in-block invZ + relu bf16 |
//       11 rowbias bf16 + fused s1/s2/s2max epilogue | 12 bf16 + cs2/v2 A-row sums
template<int BM, int BN, int MODE>
__global__ __launch_bounds__(256) void mgemm(
    const u16* __restrict__ Ag, const u16* __restrict__ B1g, const u16* __restrict__ B2g,
    int K1, int K, int lda, int ldb, long long bsA, long long bsB1,
    float* __restrict__ Cf, u16* __restrict__ Cb, int ldc, long long bsC,
    const float* __restrict__ aux1, const float* __restrict__ aux2,
    const float* __restrict__ aux3, const float* __restrict__ aux4,
    float* __restrict__ Zout)
{
  constexpr int RM = BM / 2, RN = BN / 2, MI = RM / 16, NJ = RN / 16;
  __shared__ __align__(16) u16 As[BM * 64];
  __shared__ __align__(16) u16 Bs[BN * 64];
  __shared__ float invZls[MODE == 5 ? 1024 : 1];
  const int z = blockIdx.z;
  const int n0 = blockIdx.x * BN;
  const int r0 = blockIdx.y * BM;
  const u16* Ab = Ag + (long long)z * bsA + (long long)r0 * lda;
  const u16* Bb1 = B1g + (long long)z * bsB1 + (long long)n0 * ldb;
  const int tid = threadIdx.x;
  const int lane = tid & 63;
  const int wid = tid >> 6;
  const int wr = wid >> 1, wc = wid & 1;
  const int q = lane >> 4, mlow = lane & 15;

  floatx4 acc[MI][NJ] = {};
  float zp[(BM * 8) / 256] = {};       // MODE10 row p-sums / MODE12 cs2 partials
  float vp[(BM * 8) / 256] = {};       // MODE12 v2 partials
  float ccp[(BN * 8) / 256] = {};      // MODE5 cc partials
  const bool bx0 = (blockIdx.x == 0);

  if constexpr (MODE == 5) {
    const float* Zb = aux1 + (long long)z * NI;
    for (int i = tid; i < 1024; i += 256) invZls[i] = 1.f / Zb[i];
    __syncthreads();
  }

  for (int k0 = 0; k0 < K; k0 += 64) {
    if constexpr (MODE == 10) {
      // A-tile = attention p from s1 (aux2), s2 (aux3), s2max key (Zout)
      const float* s1z = aux2 + (long long)z * NI;
      const float* s2z = aux3 + (long long)z * NI;
      const float mb = funkey(((const unsigned*)Zout)[z]);
#pragma unroll
      for (int s = 0; s < (BM * 8) / 256; s++) {
        int cid = tid + s * 256;
        int r = cid >> 3, craw = cid & 7;
        float s1r = s1z[r0 + r];
        float mr = lrelu01(s1r + mb);
        const float* sp = s2z + k0 + craw * 8;
        float4 sa = *(const float4*)sp;
        float4 sb = *(const float4*)(sp + 4);
        float p0 = __expf(lrelu01(s1r + sa.x) - mr);
        float p1 = __expf(lrelu01(s1r + sa.y) - mr);
        float p2 = __expf(lrelu01(s1r + sa.z) - mr);
        float p3 = __expf(lrelu01(s1r + sa.w) - mr);
        float p4 = __expf(lrelu01(s1r + sb.x) - mr);
        float p5 = __expf(lrelu01(s1r + sb.y) - mr);
        float p6 = __expf(lrelu01(s1r + sb.z) - mr);
        float p7 = __expf(lrelu01(s1r + sb.w) - mr);
        zp[s] += p0 + p1 + p2 + p3 + p4 + p5 + p6 + p7;
        uint4 v;
        v.x = (unsigned)f2bf(p0) | ((unsigned)f2bf(p1) << 16);
        v.y = (unsigned)f2bf(p2) | ((unsigned)f2bf(p3) << 16);
        v.z = (unsigned)f2bf(p4) | ((unsigned)f2bf(p5) << 16);
        v.w = (unsigned)f2bf(p6) | ((unsigned)f2bf(p7) << 16);
        *(uint4*)&As[(r * 8 + (craw ^ (r & 7))) * 8] = v;
      }
    } else {
      const u16* Asrc = Ab + k0;
#pragma unroll
      for (int s = 0; s < (BM * 8) / 256; s++) {
        int cid = tid + s * 256;
        int r = cid >> 3, craw = cid & 7;
        uint4 v = *(const uint4*)(Asrc + (long long)r * lda + craw * 8);
        if constexpr (MODE == 12) {
          if (bx0) {  // cs2/v2 from A rows (block-uniform branch)
            float e8[8];
            float rs = bfsum8(v, e8);
            zp[s] += rs;
            const float* c1 = aux1 + k0 + (cid & 7) * 8;
            float4 ca = *(const float4*)c1;
            float4 cb = *(const float4*)(c1 + 4);
            vp[s] += e8[0]*ca.x + e8[1]*ca.y + e8[2]*ca.z + e8[3]*ca.w
                   + e8[4]*cb.x + e8[5]*cb.y + e8[6]*cb.z + e8[7]*cb.w;
          }
        }
        *(uint4*)&As[(r * 8 + (craw ^ (r & 7))) * 8] = v;
      }
    }
    {
      const u16* Bsrc = (k0 < K1) ? (Bb1 + k0)
                                  : (B2g + (long long)n0 * ldb + (k0 - K1));
#pragma unroll
      for (int s = 0; s < (BN * 8) / 256; s++) {
        int cid = tid + s * 256;
        int r = cid >> 3, craw = cid & 7;
        uint4 v = *(const uint4*)(Bsrc + (long long)r * ldb + craw * 8);
        if constexpr (MODE == 5) {
          if (k0 < K1) {  // cc accumulation over the W half
            float e8[8];
            bfsum8(v, e8);
            const float* iz = &invZls[k0 + (cid & 7) * 8];
            ccp[s] += e8[0]*iz[0] + e8[1]*iz[1] + e8[2]*iz[2] + e8[3]*iz[3]
                    + e8[4]*iz[4] + e8[5]*iz[5] + e8[6]*iz[6] + e8[7]*iz[7];
          }
        }
        *(uint4*)&Bs[(r * 8 + (craw ^ (r & 7))) * 8] = v;
      }
    }
    __syncthreads();
#pragma unroll
    for (int kh = 0; kh < 2; kh++) {
      const int kc = kh * 4 + q;
      short8 afr[MI], bfr[NJ];
#pragma unroll
      for (int i = 0; i < MI; i++) {
        int row = wr * RM + i * 16 + mlow;
        afr[i] = *(const short8*)&As[(row * 8 + (kc ^ (row & 7))) * 8];
      }
#pragma unroll
      for (int j = 0; j < NJ; j++) {
        int row = wc * RN + j * 16 + mlow;
        bfr[j] = *(const short8*)&Bs[(row * 8 + (kc ^ (row & 7))) * 8];
      }
#pragma unroll
      for (int i = 0; i < MI; i++)
#pragma unroll
        for (int j = 0; j < NJ; j++)
          acc[i][j] = __builtin_amdgcn_mfma_f32_16x16x32_bf16(afr[i], bfr[j], acc[i][j], 0, 0, 0);
    }
    __syncthreads();
  }

  if constexpr (MODE == 3) {
    const float* sqb = aux1 + (long long)z * NI;
#pragma unroll
    for (int i = 0; i < MI; i++) {
#pragma unroll
      for (int rg = 0; rg < 4; rg++) {
        int r = r0 + wr * RM + i * 16 + q * 4 + rg;
        float sqi = sqb[r];
        float rsum = 0.f;
#pragma unroll
        for (int j = 0; j < NJ; j++) {
          int ncol = n0 + wc * RN + j * 16 + mlow;
          float d2 = fmaxf(sqi + sqb[ncol] - 2.f * acc[i][j][rg], 0.f);
          float w = __expf(__expf(-d2 * (1.f / 128.f)) + (r == ncol ? 1.f : 0.f) - 2.f);
          Cb[(long long)z * bsC + (long long)r * ldc + ncol] = f2bf(w);
          rsum += w;
        }
        rsum += __shfl_xor(rsum, 1);
        rsum += __shfl_xor(rsum, 2);
        rsum += __shfl_xor(rsum, 4);
        rsum += __shfl_xor(rsum, 8);
        if (mlow == 0) atomicAdd(&Zout[(long long)z * NI + r], rsum);
      }
    }
  } else if constexpr (MODE == 2) {
#pragma unroll
    for (int i = 0; i < MI; i++) {
#pragma unroll
      for (int rg = 0; rg < 4; rg++) {
        int r = r0 + wr * RM + i * 16 + q * 4 + rg;
        float sqp = 0.f;
#pragma unroll
        for (int j = 0; j < NJ; j++) {
          int ncol = n0 + wc * RN + j * 16 + mlow;
          float v = acc[i][j][rg] + aux1[ncol];
          Cb[(long long)z * bsC + (long long)r * ldc + ncol] = f2bf(v);
          sqp = fmaf(v, v, sqp);
        }
        sqp += __shfl_xor(sqp, 1);
        sqp += __shfl_xor(sqp, 2);
        sqp += __shfl_xor(sqp, 4);
        sqp += __shfl_xor(sqp, 8);
        if (mlow == 0) atomicAdd(&Zout[(long long)z * NI + r], sqp);
      }
    }
  } else if constexpr (MODE == 11) {
    // rowbias bf16 write + s1/s2 row-dots with w1 (aux1), w2 (aux2); bias aux3;
    // s1 -> Cf, s2 -> Zout, per-batch max -> atomicMax((unsigned*)B2g)[z]
    float* sred = (float*)As;  // [64][2] s1-halves, +128: s2-halves
#pragma unroll
    for (int i = 0; i < MI; i++) {
#pragma unroll
      for (int rg = 0; rg < 4; rg++) {
        int rloc = wr * RM + i * 16 + q * 4 + rg;
        int r = r0 + rloc;
        float rb = aux3[r];
        float ps1 = 0.f, ps2 = 0.f;
#pragma unroll
        for (int j = 0; j < NJ; j++) {
          int ncol = n0 + wc * RN + j * 16 + mlow;
          float v = acc[i][j][rg] + rb;
          Cb[(long long)z * bsC + (long long)r * ldc + ncol] = f2bf(v);
          ps1 = fmaf(v, aux1[ncol], ps1);
          ps2 = fmaf(v, aux2[ncol], ps2);
        }
        ps1 += __shfl_xor(ps1, 1); ps1 += __shfl_xor(ps1, 2);
        ps1 += __shfl_xor(ps1, 4); ps1 += __shfl_xor(ps1, 8);
        ps2 += __shfl_xor(ps2, 1); ps2 += __shfl_xor(ps2, 2);
        ps2 += __shfl_xor(ps2, 4); ps2 += __shfl_xor(ps2, 8);
        if (mlow == 0) { sred[rloc * 2 + wc] = ps1; sred[128 + rloc * 2 + wc] = ps2; }
      }
    }
    __syncthreads();
    if (tid < 64) {
      float v1 = sred[tid * 2] + sred[tid * 2 + 1];
      float v2 = sred[128 + tid * 2] + sred[128 + tid * 2 + 1];
      Cf[(long long)z * NI + r0 + tid] = v1;
      Zout[(long long)z * NI + r0 + tid] = v2;
      float mx = v2;
      for (int off = 1; off < 64; off <<= 1) mx = fmaxf(mx, __shfl_xor(mx, off));
      if (tid == 0) atomicMax((unsigned*)B2g + z, fkey(mx));
    }
  } else if constexpr (MODE == 10) {
    // in-block softmax denominator: reduce zp over craw, then epilogue
    float* zred = (float*)As;            // [64][8]
    float* zinv = (float*)As + 512;      // [64]
#pragma unroll
    for (int s = 0; s < 2; s++)
      zred[((tid >> 3) + s * 32) * 8 + (tid & 7)] = zp[s];
    __syncthreads();
    if (tid < 64) {
      float sum = 0.f;
#pragma unroll
      for (int j = 0; j < 8; j++) sum += zred[tid * 8 + j];
      zinv[tid] = 1.f / sum;
    }
    __syncthreads();
#pragma unroll
    for (int i = 0; i < MI; i++) {
#pragma unroll
      for (int j = 0; j < NJ; j++) {
#pragma unroll
        for (int rg = 0; rg < 4; rg++) {
          int rloc = wr * RM + i * 16 + q * 4 + rg;
          int ncol = n0 + wc * RN + j * 16 + mlow;
          float v = acc[i][j][rg] * zinv[rloc];
          v = fmaxf(v, 0.f);
          Cb[(long long)z * bsC + (long long)(r0 + rloc) * ldc + ncol] = f2bf(v);
        }
      }
    }
  } else if constexpr (MODE == 5) {
    // cc reduce: ccred[128][8] in As, ccls[128] at +1024 (adds cs2 via Cb cast)
    float* ccred = (float*)As;
    float* ccls = (float*)As + 1024;
    const float* cs2p = (const float*)Cb;
#pragma unroll
    for (int s = 0; s < 4; s++)
      ccred[((tid >> 3) + s * 32) * 8 + (tid & 7)] = ccp[s];
    __syncthreads();
    if (tid < 128) {
      float sum = 0.f;
#pragma unroll
      for (int j = 0; j < 8; j++) sum += ccred[tid * 8 + j];
      ccls[tid] = sum + cs2p[n0 + tid];
    }
    __syncthreads();
    float ts = 0.f, tss = 0.f;
#pragma unroll
    for (int i = 0; i < MI; i++) {
#pragma unroll
      for (int j = 0; j < NJ; j++) {
#pragma unroll
        for (int rg = 0; rg < 4; rg++) {
          int r = r0 + wr * RM + i * 16 + q * 4 + rg;
          int ncol = n0 + wc * RN + j * 16 + mlow;
          float v = acc[i][j][rg];
          v += aux3[r] * ccls[ncol - n0] + aux4[r] * aux2[ncol];
          Cf[(long long)z * bsC + (long long)r * ldc + ncol] = v;
          ts += v;
          tss = fmaf(v, v, tss);
        }
      }
    }
    // block-level LN partial stats; half = r-tile (rows 0-63 xn, 64-127 ft)
    float* red = (float*)As;  // [0,512) — disjoint from ccls [1024,1152)
    red[tid] = ts; red[256 + tid] = tss;
    __syncthreads();
    for (int st = 128; st > 0; st >>= 1) {
      if (tid < st) { red[tid] += red[tid + st]; red[256 + tid] += red[256 + tid + st]; }
      __syncthreads();
    }
    if (tid == 0) {
      const int half = r0 >> 6;
      atomicAdd(&Zout[z * 2 + half], red[0]);
      atomicAdd(&Zout[32 + z * 2 + half], red[256]);
    }
  } else {
    // MODE 4 / 6 / 12 element-wise epilogues
#pragma unroll
    for (int i = 0; i < MI; i++) {
#pragma unroll
      for (int j = 0; j < NJ; j++) {
#pragma unroll
        for (int rg = 0; rg < 4; rg++) {
          int r = r0 + wr * RM + i * 16 + q * 4 + rg;
          int ncol = n0 + wc * RN + j * 16 + mlow;
          float v = acc[i][j][rg];
          if constexpr (MODE == 4) {
            int blk = r >> 6, oo = r & 63;
            int drow = ((blk & 1) << 6) + oo;
            if (blk < 2) v = v / aux1[(long long)z * NI + ncol];  // fold 1/Zgl
            Cb[(long long)z * bsC + (long long)drow * 2048 + (long long)(blk >> 1) * 1024 + ncol] =
                f2bf(v);
          } else {
            Cb[(long long)z * bsC + (long long)r * ldc + ncol] = f2bf(v);
          }
        }
      }
    }
    if constexpr (MODE == 12) {
      if (bx0) {  // cs2 -> Cf, v2 -> Zout for this r-stripe
        float* s2red = (float*)As;         // [0,512)
        float* v2red = (float*)As + 512;   // [512,1024)
#pragma unroll
        for (int s = 0; s < 2; s++) {
          int r = (tid >> 3) + s * 32;
          s2red[r * 8 + (tid & 7)] = zp[s];
          v2red[r * 8 + (tid & 7)] = vp[s];
        }
        __syncthreads();
        if (tid < 64) {
          float a = 0.f, b = 0.f;
#pragma unroll
          for (int j = 0; j < 8; j++) { a += s2red[tid * 8 + j]; b += v2red[tid * 8 + j]; }
          Cf[r0 + tid] = a;
          Zout[r0 + tid] = b;
        }
      }
    }
  }
}

// ---------------- lap_rowsum: dr[k][i] = rsqrt(1 + rowsum(graph[k][i])) --------------
__global__ __launch_bounds__(256) void lap_rowsum(const float* __restrict__ gd,
                                                  float* __restrict__ dr)
{
  const int ki = blockIdx.x;
  const float* row = gd + (long long)ki * NI;
  float s = 0.f;
  for (int j = threadIdx.x; j < NI; j += 256) s += row[j];
  __shared__ float red[256];
  red[threadIdx.x] = s; __syncthreads();
  for (int st = 128; st > 0; st >>= 1) {
    if (threadIdx.x < st) red[threadIdx.x] += red[threadIdx.x + st];
    __syncthreads();
  }
  if (threadIdx.x == 0) dr[ki] = rsqrtf(red[0] + 1.f);
}

// ---------------- mega_prep: blockIdx-range dispatch of all prep work ----------------
__global__ __launch_bounds__(256) void mega_prep(
    const float* __restrict__ l1w, const float* __restrict__ l2w,
    const float* __restrict__ l2b, const float* __restrict__ uaiw,
    const float* __restrict__ attW, const float* __restrict__ atta,
    u16* __restrict__ stack4, float* __restrict__ rb2ext, float* __restrict__ rl2ext,
    u16* __restrict__ uaiw_bf, u16* __restrict__ attwT_bf, float* __restrict__ w12,
    const float* __restrict__ emb2w, u16* __restrict__ emb2w_bf,
    const float* __restrict__ x, const float* __restrict__ ew,
    const float* __restrict__ eb, u16* __restrict__ h0a,
    const float* __restrict__ gd, const float* __restrict__ dsum,
    u16* __restrict__ g2t, u16* __restrict__ g1,
    float* __restrict__ cs1)
{
  __shared__ float sm[1088];
  const int bid = blockIdx.x;
  const int t = threadIdx.x;
  if (bid < 98) {
    const int gid = bid * 256 + t;
    if (gid < 4096) {
      stack4[gid] = f2bf(l1w[gid]);
    } else if (gid < 8192) {
      stack4[gid] = f2bf(l2w[gid - 4096]);
    } else if (gid < 12288) {
      int tt = gid - 8192, o = tt >> 6, m = tt & 63;
      float s = 0.f;
      for (int c = 0; c < 64; c++) s = fmaf(l1w[o * 64 + c], l1w[c * 64 + m], s);
      stack4[gid] = f2bf(s);
    } else if (gid < 16384) {
      int tt = gid - 12288, o = tt >> 6, m = tt & 63;
      float s = 0.f;
      for (int c = 0; c < 64; c++) s = fmaf(l2w[o * 64 + c], l2w[c * 64 + m], s);
      stack4[gid] = f2bf(s);
    } else if (gid < 16512) {
      int r = gid - 16384;
      rb2ext[r] = (r < 64) ? 0.f : l2b[r - 64];
    } else if (gid < 16640) {
      int r = gid - 16512;
      float v = 0.f;
      if (r >= 64) { int o = r - 64; for (int c = 0; c < 64; c++) v = fmaf(l2w[o * 64 + c], l2b[c], v); }
      rl2ext[r] = v;
    } else if (gid < 20736) {
      uaiw_bf[gid - 16640] = f2bf(uaiw[gid - 16640]);
    } else if (gid < 24832) {
      int idx = gid - 20736;                 // idx = k*64 + e
      int k = idx >> 6, e = idx & 63;
      attwT_bf[idx] = f2bf(attW[e * 64 + k]);
    } else if (gid < 24960) {
      int c = gid - 24832;                   // w1[c], w2[c]: attW row-dot with a1/a2
      int cc = c & 63, which = c >> 6;
      float s = 0.f;
      for (int k = 0; k < 64; k++) s = fmaf(attW[cc * 64 + k], atta[which * 64 + k], s);
      w12[c] = s;
    }
  } else if (bid < 4194) {
    const long long i = (long long)(bid - 98) * 256 + t;
    emb2w_bf[i] = f2bf(emb2w[i]);
  } else if (bid < 5218) {
    const int be = bid - 4194;
    const int b = be >> 6, e = be & 63;
    float* w = sm;
    if (t < CI) w[t] = ew[e * CI + t];
    __syncthreads();
    const float bias = eb[e];
    const float* xb = x + (long long)b * CI * NI;
    u16* outp = h0a + (long long)be * NI;
    for (int n = t; n < NI; n += 256) {
      float a = bias;
#pragma unroll
      for (int c = 0; c < CI; c++) a = fmaf(xb[c * NI + n], w[c], a);
      outp[n] = f2bf(lrelu01(a));
    }
  } else if (bid < 9314) {
    const long long idx = (long long)(bid - 5218) * 256 + t;
    const int m = (int)(idx >> 10), j = (int)(idx & 1023);
    const float* d = dsum + NI;
    float v = (gd[NN2 + idx] + (m == j ? 1.f : 0.f)) * d[m] * d[j];
    g2t[idx] = f2bf(v);
  } else if (bid < 10338) {
    const int sub = bid - 9314;
    const int bx = (sub & 31) * 32, by = (sub >> 5) * 32;
    const int lx = t & 31, ly = t >> 5;  // 32x8
    float* tile = sm;                    // 32x33
    for (int yy = ly; yy < 32; yy += 8)
      tile[yy * 33 + lx] = gd[(long long)(by + yy) * NI + bx + lx];
    __syncthreads();
    for (int yy = ly; yy < 32; yy += 8) {
      const int i = bx + yy, j = by + lx;
      float v = (tile[lx * 33 + yy] + (i == j ? 1.f : 0.f)) * dsum[i] * dsum[j];
      g1[(long long)i * NI + j] = f2bf(v);
    }
  } else {
    const int n = bid - 10338;
    float s = 0.f;
    for (int i = t; i < NI; i += 256) s = fmaf(gd[(long long)n * NI + i], dsum[i], s);
    float* red = sm;
    red[t] = s; __syncthreads();
    for (int st = 128; st > 0; st >>= 1) {
      if (t < st) red[t] += red[t + st];
      __syncthreads();
    }
    if (t == 0) cs1[n] = dsum[n] * (red[0] + dsum[n]);
  }
}

// ---- LayerNorm apply + GELU + final gating, 64x64 tiles, LDS transpose of xu(bf16) ----
__global__ __launch_bounds__(256) void ln_final_t(const float* __restrict__ T,
                                                  const float* __restrict__ stats,
                                                  const float* __restrict__ lnw,
                                                  const float* __restrict__ lnb,
                                                  const float* __restrict__ ct,
                                                  const u16* __restrict__ xuT,
                                                  float* __restrict__ outp)
{
  __shared__ float xs[64 * 65];
  const int blk = blockIdx.x;
  const int b = blk >> 4;
  const int n0 = (blk & 15) << 6;
  const int t = threadIdx.x;
  const int tc = t & 63, tr = t >> 6;
#pragma unroll
  for (int i = 0; i < 16; i++) {
    int nn = i * 4 + tr;
    xs[tc * 65 + nn] = bf2f(xuT[((long long)b << 16) + (long long)(n0 + nn) * 64 + tc]);
  }
  __syncthreads();
  const float inv_n = 1.f / 65536.f;
  const float m0 = stats[b * 2] * inv_n;
  const float m1 = stats[b * 2 + 1] * inv_n;
  const float rs0 = rsqrtf(fmaxf(stats[32 + b * 2] * inv_n - m0 * m0, 0.f) + 1e-5f);
  const float rs1 = rsqrtf(fmaxf(stats[32 + b * 2 + 1] * inv_n - m1 * m1, 0.f) + 1e-5f);
#pragma unroll
  for (int j = 0; j < 16; j++) {
    const int c = j * 4 + tr;
    const int n = n0 + tc;
    const int rem = c * NI + n;
    const long long toff = (long long)b * S2 + rem;
    const float t0 = T[toff];
    const float t1 = T[toff + S1];
    const float w = lnw[rem], bb = lnb[rem];
    const float xn = (t0 - m0) * rs0 * w + bb;
    float ft = (t1 - m1) * rs1 * w + bb;
    ft = 0.5f * ft * (1.f + erff(ft * 0.70710678118654752f));
    const float u = xs[c * 65 + tc];
    const long long oidx = ((long long)b << 16) + rem;
    const float cn = fmaf(ft, ct[oidx] - xn, xn);
    const float el = cn > 0.f ? cn : expm1f(cn);
    outp[oidx] = fmaf(ft, el - u, u);
    outp[BCN + oidx] = cn;
  }
}

extern "C" void kernel_launch(void* const* d_in, const int* in_sizes, int n_in,
                              void* d_out, int out_size, void* d_ws, size_t ws_size,
                              hipStream_t stream)
{
  (void)in_sizes; (void)n_in; (void)out_size; (void)ws_size;
  const float* x      = (const float*)d_in[0];
  const float* ct     = (const float*)d_in[1];
  const float* gdata  = (const float*)d_in[2];
  const float* emb_w  = (const float*)d_in[3];
  const float* emb_b  = (const float*)d_in[4];
  const float* emb2_w = (const float*)d_in[5];
  const float* emb2_b = (const float*)d_in[6];
  const float* att_W  = (const float*)d_in[7];
  const float* att_a  = (const float*)d_in[8];
  // d_in[9] att_GL unused: softmax(relu(GL GL^T)) > 0 everywhere -> mask is a no-op
  const float* uai_w  = (const float*)d_in[10];
  const float* uai_b  = (const float*)d_in[11];
  const float* lin1_w = (const float*)d_in[12];
  const float* lin2_w = (const float*)d_in[13];
  const float* lin2_b = (const float*)d_in[14];
  const float* ln_w   = (const float*)d_in[15];
  const float* ln_b   = (const float*)d_in[16];
  float* outp = (float*)d_out;

  float* ws = (float*)d_ws;
  long long o = 0;
  auto af = [&](long long n) { float* p = ws + o; o += (n + 63) & ~63LL; return p; };
  auto au = [&](long long n) { return (u16*)af((n + 1) / 2); };

  float* Tacc    = af(S2 * BATCH);
  float* s1      = af(BNv);
  float* s2      = af(BNv);
  float* dsum    = af(2 * NI);
  float* cs1v    = af(NI);
  float* cs2v    = af(NI);
  float* v2v     = af(NI);
  float* rb2ext  = af(128);
  float* rl2ext  = af(128);
  float* w12     = af(128);
  // contiguous zero-init region: Zgl, sqv, stats(64), s2mU(16)
  float* zeroreg = af(2 * BNv + 80);
  float* Zgl     = zeroreg;
  float* sqv     = zeroreg + BNv;
  float* stats   = zeroreg + 2 * BNv;
  unsigned* s2mU = (unsigned*)(stats + 64);
  u16* emb2w_bf  = au(NN2);
  u16* h0a_bf    = au(S1 * BATCH);
  u16* h0Tb      = au(S1 * BATCH);   // [b][n][e]
  u16* hTb       = au(S1 * BATCH);   // [b][c][n]
  u16* xattb     = au(S1 * BATCH);   // [b][n][c]
  u16* xuaiTb    = au(S1 * BATCH);   // [b][n][c]
  u16* g1b       = au(NN2);
  u16* g2tb      = au(NN2);
  u16* G12b      = au(NN2);
  u16* Abig      = au((long long)BATCH * 128 * 2048);
  u16* stack4    = au(256 * 64);
  u16* uaiw_bf   = au(CE * CE);
  u16* attwT_bf  = au(CE * CE);
  u16* bigW      = au(BNN);  // 32 MB: gram W (att-p computed on the fly)

  hipMemsetAsync(zeroreg, 0, (2 * BNv + 80) * sizeof(float), stream);

  lap_rowsum<<<2 * NI, 256, 0, stream>>>(gdata, dsum);

  mega_prep<<<11362, 256, 0, stream>>>(
      lin1_w, lin2_w, lin2_b, uai_w, att_W, att_a,
      stack4, rb2ext, rl2ext, uaiw_bf, attwT_bf, w12,
      emb2_w, emb2w_bf, x, emb_w, emb_b, h0a_bf,
      gdata, dsum, g2tb, g1b, cs1v);

  // G12t = (g1@g2)^T, + cs2 (A rowsums) and v2 (A . cs1) from bx==0 stripe
  mgemm<64, 64, 12><<<dim3(16, 16, 1), 256, 0, stream>>>(
      g2tb, g1b, nullptr, NI, NI, NI, NI, 0, 0,
      cs2v, G12b, NI, 0, cs1v, nullptr, nullptr, nullptr, v2v);

  // h0T[b][m][e] = emb2w @ h0a^T + emb2_b, fused s1/s2/s2max epilogue
  mgemm<64, 64, 11><<<dim3(1, 16, BATCH), 256, 0, stream>>>(
      emb2w_bf, h0a_bf, (const u16*)s2mU, NI, NI, NI, NI, 0, S1,
      s1, h0Tb, CE, S1, w12, w12 + 64, emb2_b, nullptr, s2);

  // hT[b][c][n] = attW^T @ h0T^T  (K=64, bf16)
  mgemm<64, 64, 6><<<dim3(16, 1, BATCH), 256, 0, stream>>>(
      attwT_bf, h0Tb, nullptr, CE, CE, CE, CE, 0, S1,
      nullptr, hTb, NI, S1, nullptr, nullptr, nullptr, nullptr, nullptr);

  // x_att = relu((p@h)/Z); p on the fly in A-staging, Z reduced in-block
  mgemm<64, 64, 10><<<dim3(1, 16, BATCH), 256, 0, stream>>>(
      hTb, hTb, nullptr, NI, NI, NI, NI, 0, S1,
      nullptr, xattb, CE, S1, nullptr, s1, s2, nullptr, (float*)s2mU);

  // x_uaiT = x_att @ uai_w^T + uai_b (bf16, rowsq atomics into sqv)
  mgemm<64, 64, 2><<<dim3(1, 16, BATCH), 256, 0, stream>>>(
      xattb, uaiw_bf, nullptr, CE, CE, CE, CE, S1, 0,
      nullptr, xuaiTb, CE, S1, uai_b, nullptr, nullptr, nullptr, sqv);

  // gram/gl weights (128x128 tiles; exp epilogue; rowsums into Zgl)
  mgemm<128, 128, 3><<<dim3(8, 8, BATCH), 256, 0, stream>>>(
      xuaiTb, xuaiTb, nullptr, CE, CE, CE, CE, S1, S1,
      nullptr, bigW, NI, NN2, sqv, nullptr, nullptr, nullptr, Zgl);

  // Abig = [[L1u/Z | L1L1u],[L2u/Z | L2L2u]] bf16
  mgemm<64, 64, 4><<<dim3(16, 4, BATCH), 256, 0, stream>>>(
      stack4, xuaiTb, nullptr, CE, CE, CE, CE, 0, S1,
      nullptr, Abig, 0, (long long)128 * 2048, Zgl, nullptr, nullptr, nullptr, nullptr);

  // fused: Tacc = Abig @ [W ; G12t] + rank-1 (cc computed in staging) + LN stats
  mgemm<64, 128, 5><<<dim3(8, 2, BATCH), 256, 0, stream>>>(
      Abig, bigW, G12b, NI, 2 * NI, 2048, NI, (long long)128 * 2048, NN2,
      Tacc, (u16*)cs2v, NI, S2, Zgl, v2v, rb2ext, rl2ext, stats);

  ln_final_t<<<256, 256, 0, stream>>>(Tacc, stats, ln_w, ln_b, ct, xuaiTb, outp);
}

// Round 8
// 262.846 us; speedup vs baseline: 1.0805x; 1.0805x over previous
//
#include <hip/hip_runtime.h>
#include <math.h>

typedef unsigned short u16;
typedef __attribute__((ext_vector_type(8))) short short8;
typedef __attribute__((ext_vector_type(4))) float floatx4;

constexpr int BATCH = 16;
constexpr int NI = 1024;
constexpr int CE = 64;
constexpr int CI = 16;
constexpr long long NN2  = (long long)NI * NI;          // 1M
constexpr long long BCN  = (long long)BATCH * CE * NI;  // 1M
constexpr long long BNv  = (long long)BATCH * NI;       // 16K
constexpr long long BNN  = (long long)BATCH * NI * NI;  // 16M
constexpr long long S1 = (long long)CE * NI;            // 65536
constexpr long long S2 = 2 * S1;                        // 131072

__device__ __forceinline__ float lrelu01(float x) { return x > 0.f ? x : 0.01f * x; }

__device__ __forceinline__ u16 f2bf(float f) {
  unsigned u = __builtin_bit_cast(unsigned, f);
  return (u16)((u + 0x7fffu + ((u >> 16) & 1u)) >> 16);  // RNE
}
__device__ __forceinline__ float bf2f(u16 h) {
  unsigned u = ((unsigned)h) << 16;
  return __builtin_bit_cast(float, u);
}
// monotonic uint key for float atomicMax (memset-0 init safe: real-float keys > 0)
__device__ __forceinline__ unsigned fkey(float f) {
  unsigned u = __builtin_bit_cast(unsigned, f);
  return (u & 0x80000000u) ? ~u : (u | 0x80000000u);
}
__device__ __forceinline__ float funkey(unsigned k) {
  unsigned u = (k & 0x80000000u) ? (k & 0x7fffffffu) : ~k;
  return __builtin_bit_cast(float, u);
}

// ================= MFMA TN GEMM: C[r][m] = sum_k A[r][k] * Bt[m][k] ==============
// A, Bt bf16 row-major K-contiguous. BK=64, XOR-swizzled 16B chunks in LDS.
// 4 waves 2x2; wave tile (BM/2)x(BN/2); 16x16x32 MFMAs.
// MODE: 2 bf16 +colbias + rowsq atomics | 3 gram exp + rowsum | 4 Abig scatter w/ Z-div |
//       5 dual-B + rank-1 epilogue + LN-stats atomics | 6 plain bf16 |
//       10 A = attention-p on the fly + in-block invZ + relu bf16 |
//       11 rowbias bf16 + fused s1/s2/s2max epilogue
template<int BM, int BN, int MODE>
__global__ __launch_bounds__(256) void mgemm(
    const u16* __restrict__ Ag, const u16* __restrict__ B1g, const u16* __restrict__ B2g,
    int K1, int K, int lda, int ldb, long long bsA, long long bsB1,
    float* __restrict__ Cf, u16* __restrict__ Cb, int ldc, long long bsC,
    const float* __restrict__ aux1, const float* __restrict__ aux2,
    const float* __restrict__ aux3, const float* __restrict__ aux4,
    float* __restrict__ Zout)
{
  constexpr int RM = BM / 2, RN = BN / 2, MI = RM / 16, NJ = RN / 16;
  __shared__ __align__(16) u16 As[BM * 64];
  __shared__ __align__(16) u16 Bs[BN * 64];
  const int z = blockIdx.z;
  const int n0 = blockIdx.x * BN;
  const int r0 = blockIdx.y * BM;
  const u16* Ab = Ag + (long long)z * bsA + (long long)r0 * lda;
  const u16* Bb1 = B1g + (long long)z * bsB1 + (long long)n0 * ldb;
  const int tid = threadIdx.x;
  const int lane = tid & 63;
  const int wid = tid >> 6;
  const int wr = wid >> 1, wc = wid & 1;
  const int q = lane >> 4, mlow = lane & 15;

  floatx4 acc[MI][NJ] = {};
  float zp[(BM * 8) / 256] = {};       // MODE10 row p-sums

  for (int k0 = 0; k0 < K; k0 += 64) {
    if constexpr (MODE == 10) {
      // A-tile = attention p from s1 (aux2), s2 (aux3), s2max key (Zout)
      const float* s1z = aux2 + (long long)z * NI;
      const float* s2z = aux3 + (long long)z * NI;
      const float mb = funkey(((const unsigned*)Zout)[z]);
#pragma unroll
      for (int s = 0; s < (BM * 8) / 256; s++) {
        int cid = tid + s * 256;
        int r = cid >> 3, craw = cid & 7;
        float s1r = s1z[r0 + r];
        float mr = lrelu01(s1r + mb);
        const float* sp = s2z + k0 + craw * 8;
        float4 sa = *(const float4*)sp;
        float4 sb = *(const float4*)(sp + 4);
        float p0 = __expf(lrelu01(s1r + sa.x) - mr);
        float p1 = __expf(lrelu01(s1r + sa.y) - mr);
        float p2 = __expf(lrelu01(s1r + sa.z) - mr);
        float p3 = __expf(lrelu01(s1r + sa.w) - mr);
        float p4 = __expf(lrelu01(s1r + sb.x) - mr);
        float p5 = __expf(lrelu01(s1r + sb.y) - mr);
        float p6 = __expf(lrelu01(s1r + sb.z) - mr);
        float p7 = __expf(lrelu01(s1r + sb.w) - mr);
        zp[s] += p0 + p1 + p2 + p3 + p4 + p5 + p6 + p7;
        uint4 v;
        v.x = (unsigned)f2bf(p0) | ((unsigned)f2bf(p1) << 16);
        v.y = (unsigned)f2bf(p2) | ((unsigned)f2bf(p3) << 16);
        v.z = (unsigned)f2bf(p4) | ((unsigned)f2bf(p5) << 16);
        v.w = (unsigned)f2bf(p6) | ((unsigned)f2bf(p7) << 16);
        *(uint4*)&As[(r * 8 + (craw ^ (r & 7))) * 8] = v;
      }
    } else {
      const u16* Asrc = Ab + k0;
#pragma unroll
      for (int s = 0; s < (BM * 8) / 256; s++) {
        int cid = tid + s * 256;
        int r = cid >> 3, craw = cid & 7;
        uint4 v = *(const uint4*)(Asrc + (long long)r * lda + craw * 8);
        *(uint4*)&As[(r * 8 + (craw ^ (r & 7))) * 8] = v;
      }
    }
    {
      const u16* Bsrc = (k0 < K1) ? (Bb1 + k0)
                                  : (B2g + (long long)n0 * ldb + (k0 - K1));
#pragma unroll
      for (int s = 0; s < (BN * 8) / 256; s++) {
        int cid = tid + s * 256;
        int r = cid >> 3, craw = cid & 7;
        uint4 v = *(const uint4*)(Bsrc + (long long)r * ldb + craw * 8);
        *(uint4*)&Bs[(r * 8 + (craw ^ (r & 7))) * 8] = v;
      }
    }
    __syncthreads();
#pragma unroll
    for (int kh = 0; kh < 2; kh++) {
      const int kc = kh * 4 + q;
      short8 afr[MI], bfr[NJ];
#pragma unroll
      for (int i = 0; i < MI; i++) {
        int row = wr * RM + i * 16 + mlow;
        afr[i] = *(const short8*)&As[(row * 8 + (kc ^ (row & 7))) * 8];
      }
#pragma unroll
      for (int j = 0; j < NJ; j++) {
        int row = wc * RN + j * 16 + mlow;
        bfr[j] = *(const short8*)&Bs[(row * 8 + (kc ^ (row & 7))) * 8];
      }
#pragma unroll
      for (int i = 0; i < MI; i++)
#pragma unroll
        for (int j = 0; j < NJ; j++)
          acc[i][j] = __builtin_amdgcn_mfma_f32_16x16x32_bf16(afr[i], bfr[j], acc[i][j], 0, 0, 0);
    }
    __syncthreads();
  }

  if constexpr (MODE == 3) {
    const float* sqb = aux1 + (long long)z * NI;
#pragma unroll
    for (int i = 0; i < MI; i++) {
#pragma unroll
      for (int rg = 0; rg < 4; rg++) {
        int r = r0 + wr * RM + i * 16 + q * 4 + rg;
        float sqi = sqb[r];
        float rsum = 0.f;
#pragma unroll
        for (int j = 0; j < NJ; j++) {
          int ncol = n0 + wc * RN + j * 16 + mlow;
          float d2 = fmaxf(sqi + sqb[ncol] - 2.f * acc[i][j][rg], 0.f);
          float w = __expf(__expf(-d2 * (1.f / 128.f)) + (r == ncol ? 1.f : 0.f) - 2.f);
          Cb[(long long)z * bsC + (long long)r * ldc + ncol] = f2bf(w);
          rsum += w;
        }
        rsum += __shfl_xor(rsum, 1);
        rsum += __shfl_xor(rsum, 2);
        rsum += __shfl_xor(rsum, 4);
        rsum += __shfl_xor(rsum, 8);
        if (mlow == 0) atomicAdd(&Zout[(long long)z * NI + r], rsum);
      }
    }
  } else if constexpr (MODE == 2) {
#pragma unroll
    for (int i = 0; i < MI; i++) {
#pragma unroll
      for (int rg = 0; rg < 4; rg++) {
        int r = r0 + wr * RM + i * 16 + q * 4 + rg;
        float sqp = 0.f;
#pragma unroll
        for (int j = 0; j < NJ; j++) {
          int ncol = n0 + wc * RN + j * 16 + mlow;
          float v = acc[i][j][rg] + aux1[ncol];
          Cb[(long long)z * bsC + (long long)r * ldc + ncol] = f2bf(v);
          sqp = fmaf(v, v, sqp);
        }
        sqp += __shfl_xor(sqp, 1);
        sqp += __shfl_xor(sqp, 2);
        sqp += __shfl_xor(sqp, 4);
        sqp += __shfl_xor(sqp, 8);
        if (mlow == 0) atomicAdd(&Zout[(long long)z * NI + r], sqp);
      }
    }
  } else if constexpr (MODE == 11) {
    // rowbias bf16 write + s1/s2 row-dots with w1 (aux1), w2 (aux2); bias aux3;
    // s1 -> Cf, s2 -> Zout, per-batch max -> atomicMax((unsigned*)B2g)[z]
    float* sred = (float*)As;  // [64][2] s1-halves, +128: s2-halves
#pragma unroll
    for (int i = 0; i < MI; i++) {
#pragma unroll
      for (int rg = 0; rg < 4; rg++) {
        int rloc = wr * RM + i * 16 + q * 4 + rg;
        int r = r0 + rloc;
        float rb = aux3[r];
        float ps1 = 0.f, ps2 = 0.f;
#pragma unroll
        for (int j = 0; j < NJ; j++) {
          int ncol = n0 + wc * RN + j * 16 + mlow;
          float v = acc[i][j][rg] + rb;
          Cb[(long long)z * bsC + (long long)r * ldc + ncol] = f2bf(v);
          ps1 = fmaf(v, aux1[ncol], ps1);
          ps2 = fmaf(v, aux2[ncol], ps2);
        }
        ps1 += __shfl_xor(ps1, 1); ps1 += __shfl_xor(ps1, 2);
        ps1 += __shfl_xor(ps1, 4); ps1 += __shfl_xor(ps1, 8);
        ps2 += __shfl_xor(ps2, 1); ps2 += __shfl_xor(ps2, 2);
        ps2 += __shfl_xor(ps2, 4); ps2 += __shfl_xor(ps2, 8);
        if (mlow == 0) { sred[rloc * 2 + wc] = ps1; sred[128 + rloc * 2 + wc] = ps2; }
      }
    }
    __syncthreads();
    if (tid < 64) {
      float v1 = sred[tid * 2] + sred[tid * 2 + 1];
      float v2 = sred[128 + tid * 2] + sred[128 + tid * 2 + 1];
      Cf[(long long)z * NI + r0 + tid] = v1;
      Zout[(long long)z * NI + r0 + tid] = v2;
      float mx = v2;
      for (int off = 1; off < 64; off <<= 1) mx = fmaxf(mx, __shfl_xor(mx, off));
      if (tid == 0) atomicMax((unsigned*)B2g + z, fkey(mx));
    }
  } else if constexpr (MODE == 10) {
    // in-block softmax denominator: reduce zp over craw, then epilogue
    float* zred = (float*)As;            // [64][8]
    float* zinv = (float*)As + 512;      // [64]
#pragma unroll
    for (int s = 0; s < 2; s++)
      zred[((tid >> 3) + s * 32) * 8 + (tid & 7)] = zp[s];
    __syncthreads();
    if (tid < 64) {
      float sum = 0.f;
#pragma unroll
      for (int j = 0; j < 8; j++) sum += zred[tid * 8 + j];
      zinv[tid] = 1.f / sum;
    }
    __syncthreads();
#pragma unroll
    for (int i = 0; i < MI; i++) {
#pragma unroll
      for (int j = 0; j < NJ; j++) {
#pragma unroll
        for (int rg = 0; rg < 4; rg++) {
          int rloc = wr * RM + i * 16 + q * 4 + rg;
          int ncol = n0 + wc * RN + j * 16 + mlow;
          float v = acc[i][j][rg] * zinv[rloc];
          v = fmaxf(v, 0.f);
          Cb[(long long)z * bsC + (long long)(r0 + rloc) * ldc + ncol] = f2bf(v);
        }
      }
    }
  } else if constexpr (MODE == 5) {
    float ts = 0.f, tss = 0.f;
#pragma unroll
    for (int i = 0; i < MI; i++) {
#pragma unroll
      for (int j = 0; j < NJ; j++) {
#pragma unroll
        for (int rg = 0; rg < 4; rg++) {
          int r = r0 + wr * RM + i * 16 + q * 4 + rg;
          int ncol = n0 + wc * RN + j * 16 + mlow;
          float v = acc[i][j][rg];
          v += aux3[r] * aux1[(long long)z * NI + ncol] + aux4[r] * aux2[ncol];
          Cf[(long long)z * bsC + (long long)r * ldc + ncol] = v;
          ts += v;
          tss = fmaf(v, v, tss);
        }
      }
    }
    // block-level LN partial stats -> atomics; half = r-tile (rows 0-63 xn, 64-127 ft)
    float* red = (float*)As;  // 512 floats
    red[tid] = ts; red[256 + tid] = tss;
    __syncthreads();
    for (int st = 128; st > 0; st >>= 1) {
      if (tid < st) { red[tid] += red[tid + st]; red[256 + tid] += red[256 + tid + st]; }
      __syncthreads();
    }
    if (tid == 0) {
      const int half = r0 >> 6;
      atomicAdd(&Zout[z * 2 + half], red[0]);
      atomicAdd(&Zout[32 + z * 2 + half], red[256]);
    }
  } else {
    // MODE 4 / 6 element-wise epilogues
#pragma unroll
    for (int i = 0; i < MI; i++) {
#pragma unroll
      for (int j = 0; j < NJ; j++) {
#pragma unroll
        for (int rg = 0; rg < 4; rg++) {
          int r = r0 + wr * RM + i * 16 + q * 4 + rg;
          int ncol = n0 + wc * RN + j * 16 + mlow;
          float v = acc[i][j][rg];
          if constexpr (MODE == 4) {
            int blk = r >> 6, oo = r & 63;
            int drow = ((blk & 1) << 6) + oo;
            if (blk < 2) v = v / aux1[(long long)z * NI + ncol];  // fold 1/Zgl
            Cb[(long long)z * bsC + (long long)drow * 2048 + (long long)(blk >> 1) * 1024 + ncol] =
                f2bf(v);
          } else {
            Cb[(long long)z * bsC + (long long)r * ldc + ncol] = f2bf(v);
          }
        }
      }
    }
  }
}

// ---------------- lap_rowsum: dr[k][i] = rsqrt(1 + rowsum(graph[k][i])) --------------
__global__ __launch_bounds__(256) void lap_rowsum(const float* __restrict__ gd,
                                                  float* __restrict__ dr)
{
  const int ki = blockIdx.x;
  const float* row = gd + (long long)ki * NI;
  float s = 0.f;
  for (int j = threadIdx.x; j < NI; j += 256) s += row[j];
  __shared__ float red[256];
  red[threadIdx.x] = s; __syncthreads();
  for (int st = 128; st > 0; st >>= 1) {
    if (threadIdx.x < st) red[threadIdx.x] += red[threadIdx.x + st];
    __syncthreads();
  }
  if (threadIdx.x == 0) dr[ki] = rsqrtf(red[0] + 1.f);
}

// ---------------- mega_prep: blockIdx-range dispatch of all prep work ----------------
__global__ __launch_bounds__(256) void mega_prep(
    const float* __restrict__ l1w, const float* __restrict__ l2w,
    const float* __restrict__ l2b, const float* __restrict__ uaiw,
    const float* __restrict__ attW, const float* __restrict__ atta,
    u16* __restrict__ stack4, float* __restrict__ rb2ext, float* __restrict__ rl2ext,
    u16* __restrict__ uaiw_bf, u16* __restrict__ attwT_bf, float* __restrict__ w12,
    const float* __restrict__ emb2w, u16* __restrict__ emb2w_bf,
    const float* __restrict__ x, const float* __restrict__ ew,
    const float* __restrict__ eb, u16* __restrict__ h0a,
    const float* __restrict__ gd, const float* __restrict__ dsum,
    u16* __restrict__ g2t, u16* __restrict__ g1,
    float* __restrict__ cs1)
{
  __shared__ float sm[1088];
  const int bid = blockIdx.x;
  const int t = threadIdx.x;
  if (bid < 98) {
    const int gid = bid * 256 + t;
    if (gid < 4096) {
      stack4[gid] = f2bf(l1w[gid]);
    } else if (gid < 8192) {
      stack4[gid] = f2bf(l2w[gid - 4096]);
    } else if (gid < 12288) {
      int tt = gid - 8192, o = tt >> 6, m = tt & 63;
      float s = 0.f;
      for (int c = 0; c < 64; c++) s = fmaf(l1w[o * 64 + c], l1w[c * 64 + m], s);
      stack4[gid] = f2bf(s);
    } else if (gid < 16384) {
      int tt = gid - 12288, o = tt >> 6, m = tt & 63;
      float s = 0.f;
      for (int c = 0; c < 64; c++) s = fmaf(l2w[o * 64 + c], l2w[c * 64 + m], s);
      stack4[gid] = f2bf(s);
    } else if (gid < 16512) {
      int r = gid - 16384;
      rb2ext[r] = (r < 64) ? 0.f : l2b[r - 64];
    } else if (gid < 16640) {
      int r = gid - 16512;
      float v = 0.f;
      if (r >= 64) { int o = r - 64; for (int c = 0; c < 64; c++) v = fmaf(l2w[o * 64 + c], l2b[c], v); }
      rl2ext[r] = v;
    } else if (gid < 20736) {
      uaiw_bf[gid - 16640] = f2bf(uaiw[gid - 16640]);
    } else if (gid < 24832) {
      int idx = gid - 20736;                 // idx = k*64 + e
      int k = idx >> 6, e = idx & 63;
      attwT_bf[idx] = f2bf(attW[e * 64 + k]);
    } else if (gid < 24960) {
      int c = gid - 24832;                   // w1[c], w2[c]: attW row-dot with a1/a2
      int cc = c & 63, which = c >> 6;
      float s = 0.f;
      for (int k = 0; k < 64; k++) s = fmaf(attW[cc * 64 + k], atta[which * 64 + k], s);
      w12[c] = s;
    }
  } else if (bid < 4194) {
    const long long i = (long long)(bid - 98) * 256 + t;
    emb2w_bf[i] = f2bf(emb2w[i]);
  } else if (bid < 5218) {
    const int be = bid - 4194;
    const int b = be >> 6, e = be & 63;
    float* w = sm;
    if (t < CI) w[t] = ew[e * CI + t];
    __syncthreads();
    const float bias = eb[e];
    const float* xb = x + (long long)b * CI * NI;
    u16* outp = h0a + (long long)be * NI;
    for (int n = t; n < NI; n += 256) {
      float a = bias;
#pragma unroll
      for (int c = 0; c < CI; c++) a = fmaf(xb[c * NI + n], w[c], a);
      outp[n] = f2bf(lrelu01(a));
    }
  } else if (bid < 9314) {
    const long long idx = (long long)(bid - 5218) * 256 + t;
    const int m = (int)(idx >> 10), j = (int)(idx & 1023);
    const float* d = dsum + NI;
    float v = (gd[NN2 + idx] + (m == j ? 1.f : 0.f)) * d[m] * d[j];
    g2t[idx] = f2bf(v);
  } else if (bid < 10338) {
    const int sub = bid - 9314;
    const int bx = (sub & 31) * 32, by = (sub >> 5) * 32;
    const int lx = t & 31, ly = t >> 5;  // 32x8
    float* tile = sm;                    // 32x33
    for (int yy = ly; yy < 32; yy += 8)
      tile[yy * 33 + lx] = gd[(long long)(by + yy) * NI + bx + lx];
    __syncthreads();
    for (int yy = ly; yy < 32; yy += 8) {
      const int i = bx + yy, j = by + lx;
      float v = (tile[lx * 33 + yy] + (i == j ? 1.f : 0.f)) * dsum[i] * dsum[j];
      g1[(long long)i * NI + j] = f2bf(v);
    }
  } else {
    const int n = bid - 10338;
    float s = 0.f;
    for (int i = t; i < NI; i += 256) s = fmaf(gd[(long long)n * NI + i], dsum[i], s);
    float* red = sm;
    red[t] = s; __syncthreads();
    for (int st = 128; st > 0; st >>= 1) {
      if (t < st) red[t] += red[t + st];
      __syncthreads();
    }
    if (t == 0) cs1[n] = dsum[n] * (red[0] + dsum[n]);
  }
}

// cs2[m] = colsum g2; v2[m] = (cs1 @ g2)[m]
__global__ __launch_bounds__(256) void csv2_kernel(const float* __restrict__ gd1,
                                                   const float* __restrict__ d,
                                                   const float* __restrict__ cs1,
                                                   float* __restrict__ cs2,
                                                   float* __restrict__ v2)
{
  const int m = blockIdx.x;
  float s = 0.f, sv = 0.f;
  for (int n = threadIdx.x; n < NI; n += 256) {
    float g = gd1[(long long)m * NI + n] * d[n];
    s += g;
    sv = fmaf(g, cs1[n], sv);
  }
  __shared__ float r1[256], r2[256];
  r1[threadIdx.x] = s; r2[threadIdx.x] = sv; __syncthreads();
  for (int st = 128; st > 0; st >>= 1) {
    if (threadIdx.x < st) { r1[threadIdx.x] += r1[threadIdx.x + st]; r2[threadIdx.x] += r2[threadIdx.x + st]; }
    __syncthreads();
  }
  if (threadIdx.x == 0) {
    cs2[m] = d[m] * (r1[0] + d[m]);
    v2[m] = d[m] * (r2[0] + d[m] * cs1[m]);
  }
}

// cc[b][m] = sum_i W[b][m][i]/Zgl[b][i] + cs2[m]. One wave per row.
__global__ __launch_bounds__(256) void cc_kernel(const u16* __restrict__ W,
                                                 const float* __restrict__ Zgl,
                                                 const float* __restrict__ cs2,
                                                 float* __restrict__ cc)
{
  const int b = blockIdx.y;
  const int wid = threadIdx.x >> 6, lane = threadIdx.x & 63;
  const int m = blockIdx.x * 4 + wid;
  const u16* row = W + (long long)b * NN2 + (long long)m * NI;
  const float* zz = Zgl + (long long)b * NI;
  float s = 0.f;
#pragma unroll
  for (int it = 0; it < 4; it++) {
    const int j0 = it * 256 + lane * 4;
    uint2 pk = *(const uint2*)(row + j0);
    float4 zv = *(const float4*)(zz + j0);
    s += bf2f((u16)(pk.x & 0xffff)) / zv.x + bf2f((u16)(pk.x >> 16)) / zv.y
       + bf2f((u16)(pk.y & 0xffff)) / zv.z + bf2f((u16)(pk.y >> 16)) / zv.w;
  }
  for (int off = 1; off < 64; off <<= 1) s += __shfl_xor(s, off);
  if (lane == 0) cc[(long long)b * NI + m] = s + cs2[m];
}

// ---- LayerNorm apply + GELU + final gating, 64x64 tiles, LDS transpose of xu(bf16) ----
__global__ __launch_bounds__(256) void ln_final_t(const float* __restrict__ T,
                                                  const float* __restrict__ stats,
                                                  const float* __restrict__ lnw,
                                                  const float* __restrict__ lnb,
                                                  const float* __restrict__ ct,
                                                  const u16* __restrict__ xuT,
                                                  float* __restrict__ outp)
{
  __shared__ float xs[64 * 65];
  const int blk = blockIdx.x;
  const int b = blk >> 4;
  const int n0 = (blk & 15) << 6;
  const int t = threadIdx.x;
  const int tc = t & 63, tr = t >> 6;
#pragma unroll
  for (int i = 0; i < 16; i++) {
    int nn = i * 4 + tr;
    xs[tc * 65 + nn] = bf2f(xuT[((long long)b << 16) + (long long)(n0 + nn) * 64 + tc]);
  }
  __syncthreads();
  const float inv_n = 1.f / 65536.f;
  const float m0 = stats[b * 2] * inv_n;
  const float m1 = stats[b * 2 + 1] * inv_n;
  const float rs0 = rsqrtf(fmaxf(stats[32 + b * 2] * inv_n - m0 * m0, 0.f) + 1e-5f);
  const float rs1 = rsqrtf(fmaxf(stats[32 + b * 2 + 1] * inv_n - m1 * m1, 0.f) + 1e-5f);
#pragma unroll
  for (int j = 0; j < 16; j++) {
    const int c = j * 4 + tr;
    const int n = n0 + tc;
    const int rem = c * NI + n;
    const long long toff = (long long)b * S2 + rem;
    const float t0 = T[toff];
    const float t1 = T[toff + S1];
    const float w = lnw[rem], bb = lnb[rem];
    const float xn = (t0 - m0) * rs0 * w + bb;
    float ft = (t1 - m1) * rs1 * w + bb;
    ft = 0.5f * ft * (1.f + erff(ft * 0.70710678118654752f));
    const float u = xs[c * 65 + tc];
    const long long oidx = ((long long)b << 16) + rem;
    const float cn = fmaf(ft, ct[oidx] - xn, xn);
    const float el = cn > 0.f ? cn : expm1f(cn);
    outp[oidx] = fmaf(ft, el - u, u);
    outp[BCN + oidx] = cn;
  }
}

extern "C" void kernel_launch(void* const* d_in, const int* in_sizes, int n_in,
                              void* d_out, int out_size, void* d_ws, size_t ws_size,
                              hipStream_t stream)
{
  (void)in_sizes; (void)n_in; (void)out_size; (void)ws_size;
  const float* x      = (const float*)d_in[0];
  const float* ct     = (const float*)d_in[1];
  const float* gdata  = (const float*)d_in[2];
  const float* emb_w  = (const float*)d_in[3];
  const float* emb_b  = (const float*)d_in[4];
  const float* emb2_w = (const float*)d_in[5];
  const float* emb2_b = (const float*)d_in[6];
  const float* att_W  = (const float*)d_in[7];
  const float* att_a  = (const float*)d_in[8];
  // d_in[9] att_GL unused: softmax(relu(GL GL^T)) > 0 everywhere -> mask is a no-op
  const float* uai_w  = (const float*)d_in[10];
  const float* uai_b  = (const float*)d_in[11];
  const float* lin1_w = (const float*)d_in[12];
  const float* lin2_w = (const float*)d_in[13];
  const float* lin2_b = (const float*)d_in[14];
  const float* ln_w   = (const float*)d_in[15];
  const float* ln_b   = (const float*)d_in[16];
  float* outp = (float*)d_out;

  float* ws = (float*)d_ws;
  long long o = 0;
  auto af = [&](long long n) { float* p = ws + o; o += (n + 63) & ~63LL; return p; };
  auto au = [&](long long n) { return (u16*)af((n + 1) / 2); };

  float* Tacc    = af(S2 * BATCH);
  float* s1      = af(BNv);
  float* s2      = af(BNv);
  float* dsum    = af(2 * NI);
  float* cs1v    = af(NI);
  float* cs2v    = af(NI);
  float* v2v     = af(NI);
  float* ccv     = af(BNv);
  float* rb2ext  = af(128);
  float* rl2ext  = af(128);
  float* w12     = af(128);
  // contiguous zero-init region: Zgl, sqv, stats(64), s2mU(16)
  float* zeroreg = af(2 * BNv + 80);
  float* Zgl     = zeroreg;
  float* sqv     = zeroreg + BNv;
  float* stats   = zeroreg + 2 * BNv;
  unsigned* s2mU = (unsigned*)(stats + 64);
  u16* emb2w_bf  = au(NN2);
  u16* h0a_bf    = au(S1 * BATCH);
  u16* h0Tb      = au(S1 * BATCH);   // [b][n][e]
  u16* hTb       = au(S1 * BATCH);   // [b][c][n]
  u16* xattb     = au(S1 * BATCH);   // [b][n][c]
  u16* xuaiTb    = au(S1 * BATCH);   // [b][n][c]
  u16* g1b       = au(NN2);
  u16* g2tb      = au(NN2);
  u16* G12b      = au(NN2);
  u16* Abig      = au((long long)BATCH * 128 * 2048);
  u16* stack4    = au(256 * 64);
  u16* uaiw_bf   = au(CE * CE);
  u16* attwT_bf  = au(CE * CE);
  u16* bigW      = au(BNN);  // 32 MB: gram W (att-p computed on the fly)

  hipMemsetAsync(zeroreg, 0, (2 * BNv + 80) * sizeof(float), stream);

  lap_rowsum<<<2 * NI, 256, 0, stream>>>(gdata, dsum);

  mega_prep<<<11362, 256, 0, stream>>>(
      lin1_w, lin2_w, lin2_b, uai_w, att_W, att_a,
      stack4, rb2ext, rl2ext, uaiw_bf, attwT_bf, w12,
      emb2_w, emb2w_bf, x, emb_w, emb_b, h0a_bf,
      gdata, dsum, g2tb, g1b, cs1v);

  csv2_kernel<<<NI, 256, 0, stream>>>(gdata + NN2, dsum + NI, cs1v, cs2v, v2v);

  // G12t = (g1@g2)^T = TN(A=g2t, Bt=g1)
  mgemm<64, 64, 6><<<dim3(16, 16, 1), 256, 0, stream>>>(
      g2tb, g1b, nullptr, NI, NI, NI, NI, 0, 0,
      nullptr, G12b, NI, 0, nullptr, nullptr, nullptr, nullptr, nullptr);

  // h0T[b][m][e] = emb2w @ h0a^T + emb2_b, fused s1/s2/s2max epilogue
  mgemm<64, 64, 11><<<dim3(1, 16, BATCH), 256, 0, stream>>>(
      emb2w_bf, h0a_bf, (const u16*)s2mU, NI, NI, NI, NI, 0, S1,
      s1, h0Tb, CE, S1, w12, w12 + 64, emb2_b, nullptr, s2);

  // hT[b][c][n] = attW^T @ h0T^T  (K=64, bf16)
  mgemm<64, 64, 6><<<dim3(16, 1, BATCH), 256, 0, stream>>>(
      attwT_bf, h0Tb, nullptr, CE, CE, CE, CE, 0, S1,
      nullptr, hTb, NI, S1, nullptr, nullptr, nullptr, nullptr, nullptr);

  // x_att = relu((p@h)/Z); p on the fly in A-staging, Z reduced in-block
  mgemm<64, 64, 10><<<dim3(1, 16, BATCH), 256, 0, stream>>>(
      hTb, hTb, nullptr, NI, NI, NI, NI, 0, S1,
      nullptr, xattb, CE, S1, nullptr, s1, s2, nullptr, (float*)s2mU);

  // x_uaiT = x_att @ uai_w^T + uai_b (bf16, rowsq atomics into sqv)
  mgemm<64, 64, 2><<<dim3(1, 16, BATCH), 256, 0, stream>>>(
      xattb, uaiw_bf, nullptr, CE, CE, CE, CE, S1, 0,
      nullptr, xuaiTb, CE, S1, uai_b, nullptr, nullptr, nullptr, sqv);

  // gram/gl weights (128x128 tiles; exp epilogue; rowsums into Zgl)
  mgemm<128, 128, 3><<<dim3(8, 8, BATCH), 256, 0, stream>>>(
      xuaiTb, xuaiTb, nullptr, CE, CE, CE, CE, S1, S1,
      nullptr, bigW, NI, NN2, sqv, nullptr, nullptr, nullptr, Zgl);

  cc_kernel<<<dim3(NI / 4, BATCH), 256, 0, stream>>>(bigW, Zgl, cs2v, ccv);

  // Abig = [[L1u/Z | L1L1u],[L2u/Z | L2L2u]] bf16
  mgemm<64, 64, 4><<<dim3(16, 4, BATCH), 256, 0, stream>>>(
      stack4, xuaiTb, nullptr, CE, CE, CE, CE, 0, S1,
      nullptr, Abig, 0, (long long)128 * 2048, Zgl, nullptr, nullptr, nullptr, nullptr);

  // fused: Tacc = Abig @ [W ; G12t] + b2 (x) cc + (L2 b2) (x) v2, + LN-stats atomics
  // BN=64 / 512 blocks = 2 blocks/CU for latency hiding (r7's 256-block version stalled)
  mgemm<64, 64, 5><<<dim3(16, 2, BATCH), 256, 0, stream>>>(
      Abig, bigW, G12b, NI, 2 * NI, 2048, NI, (long long)128 * 2048, NN2,
      Tacc, nullptr, NI, S2, ccv, v2v, rb2ext, rl2ext, stats);

  ln_final_t<<<256, 256, 0, stream>>>(Tacc, stats, ln_w, ln_b, ct, xuaiTb, outp);
}

// Round 9
// 257.233 us; speedup vs baseline: 1.1041x; 1.0218x over previous
//
#include <hip/hip_runtime.h>
#include <math.h>

typedef unsigned short u16;
typedef __attribute__((ext_vector_type(8))) short short8;
typedef __attribute__((ext_vector_type(4))) float floatx4;

constexpr int BATCH = 16;
constexpr int NI = 1024;
constexpr int CE = 64;
constexpr int CI = 16;
constexpr long long NN2  = (long long)NI * NI;          // 1M
constexpr long long BCN  = (long long)BATCH * CE * NI;  // 1M
constexpr long long BNv  = (long long)BATCH * NI;       // 16K
constexpr long long BNN  = (long long)BATCH * NI * NI;  // 16M
constexpr long long S1 = (long long)CE * NI;            // 65536
constexpr long long S2 = 2 * S1;                        // 131072

__device__ __forceinline__ float lrelu01(float x) { return x > 0.f ? x : 0.01f * x; }

__device__ __forceinline__ u16 f2bf(float f) {
  unsigned u = __builtin_bit_cast(unsigned, f);
  return (u16)((u + 0x7fffu + ((u >> 16) & 1u)) >> 16);  // RNE
}
__device__ __forceinline__ float bf2f(u16 h) {
  unsigned u = ((unsigned)h) << 16;
  return __builtin_bit_cast(float, u);
}
// monotonic uint key for float atomicMax (memset-0 init safe: real-float keys > 0)
__device__ __forceinline__ unsigned fkey(float f) {
  unsigned u = __builtin_bit_cast(unsigned, f);
  return (u & 0x80000000u) ? ~u : (u | 0x80000000u);
}
__device__ __forceinline__ float funkey(unsigned k) {
  unsigned u = (k & 0x80000000u) ? (k & 0x7fffffffu) : ~k;
  return __builtin_bit_cast(float, u);
}

// ================= MFMA TN GEMM: C[r][m] = sum_k A[r][k] * Bt[m][k] ==============
// A, Bt bf16 row-major K-contiguous. BK=64, XOR-swizzled 16B chunks in LDS.
// 4 waves 2x2; wave tile (BM/2)x(BN/2); 16x16x32 MFMAs.
// MODE: 3 gram exp + rowsum | 4 Abig scatter w/ Z-div |
//       5 dual-B + rank-1 epilogue + LN-stats atomics | 6 plain bf16 |
//       11 rowbias bf16 + fused s1/s2/s2max epilogue |
//       13 A = attention-p on the fly + in-block invZ + relu + SECOND MFMA stage
//          (x_uai = relu(x_att) @ uaiw^T + uai_b, rowsq atomics) — 2 GEMMs, 1 kernel
template<int BM, int BN, int MODE>
__global__ __launch_bounds__(256) void mgemm(
    const u16* __restrict__ Ag, const u16* __restrict__ B1g, const u16* __restrict__ B2g,
    int K1, int K, int lda, int ldb, long long bsA, long long bsB1,
    float* __restrict__ Cf, u16* __restrict__ Cb, int ldc, long long bsC,
    const float* __restrict__ aux1, const float* __restrict__ aux2,
    const float* __restrict__ aux3, const float* __restrict__ aux4,
    float* __restrict__ Zout)
{
  constexpr int RM = BM / 2, RN = BN / 2, MI = RM / 16, NJ = RN / 16;
  __shared__ __align__(16) u16 As[BM * 64];
  __shared__ __align__(16) u16 Bs[BN * 64];
  __shared__ __align__(16) u16 xa[MODE == 13 ? 32 * 72 : 1];  // stage-2 A tile (padded)
  const int z = blockIdx.z;
  const int n0 = blockIdx.x * BN;
  const int r0 = blockIdx.y * BM;
  const u16* Ab = Ag + (long long)z * bsA + (long long)r0 * lda;
  const u16* Bb1 = B1g + (long long)z * bsB1 + (long long)n0 * ldb;
  const int tid = threadIdx.x;
  const int lane = tid & 63;
  const int wid = tid >> 6;
  const int wr = wid >> 1, wc = wid & 1;
  const int q = lane >> 4, mlow = lane & 15;

  floatx4 acc[MI][NJ] = {};
  float zp[(BM * 8) / 256] = {};       // MODE13 row p-sums

  for (int k0 = 0; k0 < K; k0 += 64) {
    if constexpr (MODE == 13) {
      // A-tile = attention p from s1 (aux2), s2 (aux3), s2max key (aux4)
      const float* s1z = aux2 + (long long)z * NI;
      const float* s2z = aux3 + (long long)z * NI;
      const float mb = funkey(((const unsigned*)aux4)[z]);
#pragma unroll
      for (int s = 0; s < (BM * 8) / 256; s++) {
        int cid = tid + s * 256;
        int r = cid >> 3, craw = cid & 7;
        float s1r = s1z[r0 + r];
        float mr = lrelu01(s1r + mb);
        const float* sp = s2z + k0 + craw * 8;
        float4 sa = *(const float4*)sp;
        float4 sb = *(const float4*)(sp + 4);
        float p0 = __expf(lrelu01(s1r + sa.x) - mr);
        float p1 = __expf(lrelu01(s1r + sa.y) - mr);
        float p2 = __expf(lrelu01(s1r + sa.z) - mr);
        float p3 = __expf(lrelu01(s1r + sa.w) - mr);
        float p4 = __expf(lrelu01(s1r + sb.x) - mr);
        float p5 = __expf(lrelu01(s1r + sb.y) - mr);
        float p6 = __expf(lrelu01(s1r + sb.z) - mr);
        float p7 = __expf(lrelu01(s1r + sb.w) - mr);
        zp[s] += p0 + p1 + p2 + p3 + p4 + p5 + p6 + p7;
        uint4 v;
        v.x = (unsigned)f2bf(p0) | ((unsigned)f2bf(p1) << 16);
        v.y = (unsigned)f2bf(p2) | ((unsigned)f2bf(p3) << 16);
        v.z = (unsigned)f2bf(p4) | ((unsigned)f2bf(p5) << 16);
        v.w = (unsigned)f2bf(p6) | ((unsigned)f2bf(p7) << 16);
        *(uint4*)&As[(r * 8 + (craw ^ (r & 7))) * 8] = v;
      }
    } else {
      const u16* Asrc = Ab + k0;
#pragma unroll
      for (int s = 0; s < (BM * 8) / 256; s++) {
        int cid = tid + s * 256;
        int r = cid >> 3, craw = cid & 7;
        uint4 v = *(const uint4*)(Asrc + (long long)r * lda + craw * 8);
        *(uint4*)&As[(r * 8 + (craw ^ (r & 7))) * 8] = v;
      }
    }
    {
      const u16* Bsrc = (k0 < K1) ? (Bb1 + k0)
                                  : (B2g + (long long)n0 * ldb + (k0 - K1));
#pragma unroll
      for (int s = 0; s < (BN * 8) / 256; s++) {
        int cid = tid + s * 256;
        int r = cid >> 3, craw = cid & 7;
        uint4 v = *(const uint4*)(Bsrc + (long long)r * ldb + craw * 8);
        *(uint4*)&Bs[(r * 8 + (craw ^ (r & 7))) * 8] = v;
      }
    }
    __syncthreads();
#pragma unroll
    for (int kh = 0; kh < 2; kh++) {
      const int kc = kh * 4 + q;
      short8 afr[MI], bfr[NJ];
#pragma unroll
      for (int i = 0; i < MI; i++) {
        int row = wr * RM + i * 16 + mlow;
        afr[i] = *(const short8*)&As[(row * 8 + (kc ^ (row & 7))) * 8];
      }
#pragma unroll
      for (int j = 0; j < NJ; j++) {
        int row = wc * RN + j * 16 + mlow;
        bfr[j] = *(const short8*)&Bs[(row * 8 + (kc ^ (row & 7))) * 8];
      }
#pragma unroll
      for (int i = 0; i < MI; i++)
#pragma unroll
        for (int j = 0; j < NJ; j++)
          acc[i][j] = __builtin_amdgcn_mfma_f32_16x16x32_bf16(afr[i], bfr[j], acc[i][j], 0, 0, 0);
    }
    __syncthreads();
  }

  if constexpr (MODE == 3) {
    const float* sqb = aux1 + (long long)z * NI;
#pragma unroll
    for (int i = 0; i < MI; i++) {
#pragma unroll
      for (int rg = 0; rg < 4; rg++) {
        int r = r0 + wr * RM + i * 16 + q * 4 + rg;
        float sqi = sqb[r];
        float rsum = 0.f;
#pragma unroll
        for (int j = 0; j < NJ; j++) {
          int ncol = n0 + wc * RN + j * 16 + mlow;
          float d2 = fmaxf(sqi + sqb[ncol] - 2.f * acc[i][j][rg], 0.f);
          float w = __expf(__expf(-d2 * (1.f / 128.f)) + (r == ncol ? 1.f : 0.f) - 2.f);
          Cb[(long long)z * bsC + (long long)r * ldc + ncol] = f2bf(w);
          rsum += w;
        }
        rsum += __shfl_xor(rsum, 1);
        rsum += __shfl_xor(rsum, 2);
        rsum += __shfl_xor(rsum, 4);
        rsum += __shfl_xor(rsum, 8);
        if (mlow == 0) atomicAdd(&Zout[(long long)z * NI + r], rsum);
      }
    }
  } else if constexpr (MODE == 11) {
    // rowbias bf16 write + s1/s2 row-dots with w1 (aux1), w2 (aux2); bias aux3;
    // s1 -> Cf, s2 -> Zout, per-batch max -> atomicMax((unsigned*)B2g)[z]
    float* sred = (float*)As;  // [64][2] s1-halves, +128: s2-halves
#pragma unroll
    for (int i = 0; i < MI; i++) {
#pragma unroll
      for (int rg = 0; rg < 4; rg++) {
        int rloc = wr * RM + i * 16 + q * 4 + rg;
        int r = r0 + rloc;
        float rb = aux3[r];
        float ps1 = 0.f, ps2 = 0.f;
#pragma unroll
        for (int j = 0; j < NJ; j++) {
          int ncol = n0 + wc * RN + j * 16 + mlow;
          float v = acc[i][j][rg] + rb;
          Cb[(long long)z * bsC + (long long)r * ldc + ncol] = f2bf(v);
          ps1 = fmaf(v, aux1[ncol], ps1);
          ps2 = fmaf(v, aux2[ncol], ps2);
        }
        ps1 += __shfl_xor(ps1, 1); ps1 += __shfl_xor(ps1, 2);
        ps1 += __shfl_xor(ps1, 4); ps1 += __shfl_xor(ps1, 8);
        ps2 += __shfl_xor(ps2, 1); ps2 += __shfl_xor(ps2, 2);
        ps2 += __shfl_xor(ps2, 4); ps2 += __shfl_xor(ps2, 8);
        if (mlow == 0) { sred[rloc * 2 + wc] = ps1; sred[128 + rloc * 2 + wc] = ps2; }
      }
    }
    __syncthreads();
    if (tid < 64) {
      float v1 = sred[tid * 2] + sred[tid * 2 + 1];
      float v2 = sred[128 + tid * 2] + sred[128 + tid * 2 + 1];
      Cf[(long long)z * NI + r0 + tid] = v1;
      Zout[(long long)z * NI + r0 + tid] = v2;
      float mx = v2;
      for (int off = 1; off < 64; off <<= 1) mx = fmaxf(mx, __shfl_xor(mx, off));
      if (tid == 0) atomicMax((unsigned*)B2g + z, fkey(mx));
    }
  } else if constexpr (MODE == 13) {
    // ---- stage-1 finish: in-block softmax denominator (BM=32) ----
    float* zred = (float*)xa;            // [32][8]
    float* zinv = (float*)xa + 256;      // [32]
    zred[(tid >> 3) * 8 + (tid & 7)] = zp[0];
    __syncthreads();
    if (tid < 32) {
      float sum = 0.f;
#pragma unroll
      for (int j = 0; j < 8; j++) sum += zred[tid * 8 + j];
      zinv[tid] = 1.f / sum;
    }
    __syncthreads();
    float zr[4];
#pragma unroll
    for (int rg = 0; rg < 4; rg++) zr[rg] = zinv[wr * 16 + q * 4 + rg];
    __syncthreads();  // all zinv reads done before xa overwrite
    // ---- x_att tile (relu, scaled) -> xa as A-fragments; uaiw -> Bs ----
#pragma unroll
    for (int j = 0; j < NJ; j++) {
#pragma unroll
      for (int rg = 0; rg < 4; rg++) {
        int row = wr * 16 + q * 4 + rg;
        int col = wc * RN + j * 16 + mlow;
        float v = fmaxf(acc[0][j][rg] * zr[rg], 0.f);
        xa[row * 72 + col] = f2bf(v);
      }
    }
#pragma unroll
    for (int s = 0; s < 2; s++) {
      int cid = tid + s * 256;
      int r = cid >> 3, craw = cid & 7;
      *(uint4*)&Bs[(r * 8 + (craw ^ (r & 7))) * 8] =
          *(const uint4*)(B2g + r * 64 + craw * 8);
    }
    __syncthreads();
    // ---- stage-2: x_uai tile = xa @ uaiw^T (K=64) ----
    floatx4 acc2[2] = {};
#pragma unroll
    for (int kh = 0; kh < 2; kh++) {
      const int kc = kh * 4 + q;
      short8 a2 = *(const short8*)&xa[(wr * 16 + mlow) * 72 + kc * 8];
#pragma unroll
      for (int j = 0; j < 2; j++) {
        int orow = wc * 32 + j * 16 + mlow;
        short8 b2 = *(const short8*)&Bs[(orow * 8 + (kc ^ (orow & 7))) * 8];
        acc2[j] = __builtin_amdgcn_mfma_f32_16x16x32_bf16(a2, b2, acc2[j], 0, 0, 0);
      }
    }
#pragma unroll
    for (int rg = 0; rg < 4; rg++) {
      int row = r0 + wr * 16 + q * 4 + rg;
      float sqp = 0.f;
#pragma unroll
      for (int j = 0; j < 2; j++) {
        int o = wc * 32 + j * 16 + mlow;
        float v = acc2[j][rg] + aux1[o];
        Cb[(long long)z * bsC + (long long)row * ldc + o] = f2bf(v);
        sqp = fmaf(v, v, sqp);
      }
      sqp += __shfl_xor(sqp, 1);
      sqp += __shfl_xor(sqp, 2);
      sqp += __shfl_xor(sqp, 4);
      sqp += __shfl_xor(sqp, 8);
      if (mlow == 0) atomicAdd(&Zout[(long long)z * NI + row], sqp);
    }
  } else if constexpr (MODE == 5) {
    float ts = 0.f, tss = 0.f;
#pragma unroll
    for (int i = 0; i < MI; i++) {
#pragma unroll
      for (int j = 0; j < NJ; j++) {
#pragma unroll
        for (int rg = 0; rg < 4; rg++) {
          int r = r0 + wr * RM + i * 16 + q * 4 + rg;
          int ncol = n0 + wc * RN + j * 16 + mlow;
          float v = acc[i][j][rg];
          v += aux3[r] * aux1[(long long)z * NI + ncol] + aux4[r] * aux2[ncol];
          Cf[(long long)z * bsC + (long long)r * ldc + ncol] = v;
          ts += v;
          tss = fmaf(v, v, tss);
        }
      }
    }
    // block-level LN partial stats -> atomics; half = r-tile (rows 0-63 xn, 64-127 ft)
    float* red = (float*)As;  // 512 floats
    red[tid] = ts; red[256 + tid] = tss;
    __syncthreads();
    for (int st = 128; st > 0; st >>= 1) {
      if (tid < st) { red[tid] += red[tid + st]; red[256 + tid] += red[256 + tid + st]; }
      __syncthreads();
    }
    if (tid == 0) {
      const int half = r0 >> 6;
      atomicAdd(&Zout[z * 2 + half], red[0]);
      atomicAdd(&Zout[32 + z * 2 + half], red[256]);
    }
  } else {
    // MODE 4 / 6 element-wise epilogues
#pragma unroll
    for (int i = 0; i < MI; i++) {
#pragma unroll
      for (int j = 0; j < NJ; j++) {
#pragma unroll
        for (int rg = 0; rg < 4; rg++) {
          int r = r0 + wr * RM + i * 16 + q * 4 + rg;
          int ncol = n0 + wc * RN + j * 16 + mlow;
          float v = acc[i][j][rg];
          if constexpr (MODE == 4) {
            int blk = r >> 6, oo = r & 63;
            int drow = ((blk & 1) << 6) + oo;
            if (blk < 2) v = v / aux1[(long long)z * NI + ncol];  // fold 1/Zgl
            Cb[(long long)z * bsC + (long long)drow * 2048 + (long long)(blk >> 1) * 1024 + ncol] =
                f2bf(v);
          } else {
            Cb[(long long)z * bsC + (long long)r * ldc + ncol] = f2bf(v);
          }
        }
      }
    }
  }
}

// ---------------- lap_rowsum: dr[k][i] = rsqrt(1 + rowsum(graph[k][i])) --------------
__global__ __launch_bounds__(256) void lap_rowsum(const float* __restrict__ gd,
                                                  float* __restrict__ dr)
{
  const int ki = blockIdx.x;
  const float* row = gd + (long long)ki * NI;
  float s = 0.f;
  for (int j = threadIdx.x; j < NI; j += 256) s += row[j];
  __shared__ float red[256];
  red[threadIdx.x] = s; __syncthreads();
  for (int st = 128; st > 0; st >>= 1) {
    if (threadIdx.x < st) red[threadIdx.x] += red[threadIdx.x + st];
    __syncthreads();
  }
  if (threadIdx.x == 0) dr[ki] = rsqrtf(red[0] + 1.f);
}

// ---------------- mega_prep: blockIdx-range dispatch of all prep work ----------------
__global__ __launch_bounds__(256) void mega_prep(
    const float* __restrict__ l1w, const float* __restrict__ l2w,
    const float* __restrict__ l2b, const float* __restrict__ uaiw,
    const float* __restrict__ attW, const float* __restrict__ atta,
    u16* __restrict__ stack4, float* __restrict__ rb2ext, float* __restrict__ rl2ext,
    u16* __restrict__ uaiw_bf, u16* __restrict__ attwT_bf, float* __restrict__ w12,
    const float* __restrict__ emb2w, u16* __restrict__ emb2w_bf,
    const float* __restrict__ x, const float* __restrict__ ew,
    const float* __restrict__ eb, u16* __restrict__ h0a,
    const float* __restrict__ gd, const float* __restrict__ dsum,
    u16* __restrict__ g2t, u16* __restrict__ g1,
    float* __restrict__ cs1)
{
  __shared__ float sm[1088];
  const int bid = blockIdx.x;
  const int t = threadIdx.x;
  if (bid < 98) {
    const int gid = bid * 256 + t;
    if (gid < 4096) {
      stack4[gid] = f2bf(l1w[gid]);
    } else if (gid < 8192) {
      stack4[gid] = f2bf(l2w[gid - 4096]);
    } else if (gid < 12288) {
      int tt = gid - 8192, o = tt >> 6, m = tt & 63;
      float s = 0.f;
      for (int c = 0; c < 64; c++) s = fmaf(l1w[o * 64 + c], l1w[c * 64 + m], s);
      stack4[gid] = f2bf(s);
    } else if (gid < 16384) {
      int tt = gid - 12288, o = tt >> 6, m = tt & 63;
      float s = 0.f;
      for (int c = 0; c < 64; c++) s = fmaf(l2w[o * 64 + c], l2w[c * 64 + m], s);
      stack4[gid] = f2bf(s);
    } else if (gid < 16512) {
      int r = gid - 16384;
      rb2ext[r] = (r < 64) ? 0.f : l2b[r - 64];
    } else if (gid < 16640) {
      int r = gid - 16512;
      float v = 0.f;
      if (r >= 64) { int o = r - 64; for (int c = 0; c < 64; c++) v = fmaf(l2w[o * 64 + c], l2b[c], v); }
      rl2ext[r] = v;
    } else if (gid < 20736) {
      uaiw_bf[gid - 16640] = f2bf(uaiw[gid - 16640]);
    } else if (gid < 24832) {
      int idx = gid - 20736;                 // idx = k*64 + e
      int k = idx >> 6, e = idx & 63;
      attwT_bf[idx] = f2bf(attW[e * 64 + k]);
    } else if (gid < 24960) {
      int c = gid - 24832;                   // w1[c], w2[c]: attW row-dot with a1/a2
      int cc = c & 63, which = c >> 6;
      float s = 0.f;
      for (int k = 0; k < 64; k++) s = fmaf(attW[cc * 64 + k], atta[which * 64 + k], s);
      w12[c] = s;
    }
  } else if (bid < 4194) {
    const long long i = (long long)(bid - 98) * 256 + t;
    emb2w_bf[i] = f2bf(emb2w[i]);
  } else if (bid < 5218) {
    const int be = bid - 4194;
    const int b = be >> 6, e = be & 63;
    float* w = sm;
    if (t < CI) w[t] = ew[e * CI + t];
    __syncthreads();
    const float bias = eb[e];
    const float* xb = x + (long long)b * CI * NI;
    u16* outp = h0a + (long long)be * NI;
    for (int n = t; n < NI; n += 256) {
      float a = bias;
#pragma unroll
      for (int c = 0; c < CI; c++) a = fmaf(xb[c * NI + n], w[c], a);
      outp[n] = f2bf(lrelu01(a));
    }
  } else if (bid < 9314) {
    const long long idx = (long long)(bid - 5218) * 256 + t;
    const int m = (int)(idx >> 10), j = (int)(idx & 1023);
    const float* d = dsum + NI;
    float v = (gd[NN2 + idx] + (m == j ? 1.f : 0.f)) * d[m] * d[j];
    g2t[idx] = f2bf(v);
  } else if (bid < 10338) {
    const int sub = bid - 9314;
    const int bx = (sub & 31) * 32, by = (sub >> 5) * 32;
    const int lx = t & 31, ly = t >> 5;  // 32x8
    float* tile = sm;                    // 32x33
    for (int yy = ly; yy < 32; yy += 8)
      tile[yy * 33 + lx] = gd[(long long)(by + yy) * NI + bx + lx];
    __syncthreads();
    for (int yy = ly; yy < 32; yy += 8) {
      const int i = bx + yy, j = by + lx;
      float v = (tile[lx * 33 + yy] + (i == j ? 1.f : 0.f)) * dsum[i] * dsum[j];
      g1[(long long)i * NI + j] = f2bf(v);
    }
  } else {
    const int n = bid - 10338;
    float s = 0.f;
    for (int i = t; i < NI; i += 256) s = fmaf(gd[(long long)n * NI + i], dsum[i], s);
    float* red = sm;
    red[t] = s; __syncthreads();
    for (int st = 128; st > 0; st >>= 1) {
      if (t < st) red[t] += red[t + st];
      __syncthreads();
    }
    if (t == 0) cs1[n] = dsum[n] * (red[0] + dsum[n]);
  }
}

// cs2[m] = colsum g2; v2[m] = (cs1 @ g2)[m]
__global__ __launch_bounds__(256) void csv2_kernel(const float* __restrict__ gd1,
                                                   const float* __restrict__ d,
                                                   const float* __restrict__ cs1,
                                                   float* __restrict__ cs2,
                                                   float* __restrict__ v2)
{
  const int m = blockIdx.x;
  float s = 0.f, sv = 0.f;
  for (int n = threadIdx.x; n < NI; n += 256) {
    float g = gd1[(long long)m * NI + n] * d[n];
    s += g;
    sv = fmaf(g, cs1[n], sv);
  }
  __shared__ float r1[256], r2[256];
  r1[threadIdx.x] = s; r2[threadIdx.x] = sv; __syncthreads();
  for (int st = 128; st > 0; st >>= 1) {
    if (threadIdx.x < st) { r1[threadIdx.x] += r1[threadIdx.x + st]; r2[threadIdx.x] += r2[threadIdx.x + st]; }
    __syncthreads();
  }
  if (threadIdx.x == 0) {
    cs2[m] = d[m] * (r1[0] + d[m]);
    v2[m] = d[m] * (r2[0] + d[m] * cs1[m]);
  }
}

// cc[b][m] = sum_i W[b][m][i]/Zgl[b][i] + cs2[m]. One wave per row.
__global__ __launch_bounds__(256) void cc_kernel(const u16* __restrict__ W,
                                                 const float* __restrict__ Zgl,
                                                 const float* __restrict__ cs2,
                                                 float* __restrict__ cc)
{
  const int b = blockIdx.y;
  const int wid = threadIdx.x >> 6, lane = threadIdx.x & 63;
  const int m = blockIdx.x * 4 + wid;
  const u16* row = W + (long long)b * NN2 + (long long)m * NI;
  const float* zz = Zgl + (long long)b * NI;
  float s = 0.f;
#pragma unroll
  for (int it = 0; it < 4; it++) {
    const int j0 = it * 256 + lane * 4;
    uint2 pk = *(const uint2*)(row + j0);
    float4 zv = *(const float4*)(zz + j0);
    s += bf2f((u16)(pk.x & 0xffff)) / zv.x + bf2f((u16)(pk.x >> 16)) / zv.y
       + bf2f((u16)(pk.y & 0xffff)) / zv.z + bf2f((u16)(pk.y >> 16)) / zv.w;
  }
  for (int off = 1; off < 64; off <<= 1) s += __shfl_xor(s, off);
  if (lane == 0) cc[(long long)b * NI + m] = s + cs2[m];
}

// ---- LayerNorm apply + GELU + final gating, 64x64 tiles, LDS transpose of xu(bf16) ----
__global__ __launch_bounds__(256) void ln_final_t(const float* __restrict__ T,
                                                  const float* __restrict__ stats,
                                                  const float* __restrict__ lnw,
                                                  const float* __restrict__ lnb,
                                                  const float* __restrict__ ct,
                                                  const u16* __restrict__ xuT,
                                                  float* __restrict__ outp)
{
  __shared__ float xs[64 * 65];
  const int blk = blockIdx.x;
  const int b = blk >> 4;
  const int n0 = (blk & 15) << 6;
  const int t = threadIdx.x;
  const int tc = t & 63, tr = t >> 6;
#pragma unroll
  for (int i = 0; i < 16; i++) {
    int nn = i * 4 + tr;
    xs[tc * 65 + nn] = bf2f(xuT[((long long)b << 16) + (long long)(n0 + nn) * 64 + tc]);
  }
  __syncthreads();
  const float inv_n = 1.f / 65536.f;
  const float m0 = stats[b * 2] * inv_n;
  const float m1 = stats[b * 2 + 1] * inv_n;
  const float rs0 = rsqrtf(fmaxf(stats[32 + b * 2] * inv_n - m0 * m0, 0.f) + 1e-5f);
  const float rs1 = rsqrtf(fmaxf(stats[32 + b * 2 + 1] * inv_n - m1 * m1, 0.f) + 1e-5f);
#pragma unroll
  for (int j = 0; j < 16; j++) {
    const int c = j * 4 + tr;
    const int n = n0 + tc;
    const int rem = c * NI + n;
    const long long toff = (long long)b * S2 + rem;
    const float t0 = T[toff];
    const float t1 = T[toff + S1];
    const float w = lnw[rem], bb = lnb[rem];
    const float xn = (t0 - m0) * rs0 * w + bb;
    float ft = (t1 - m1) * rs1 * w + bb;
    ft = 0.5f * ft * (1.f + erff(ft * 0.70710678118654752f));
    const float u = xs[c * 65 + tc];
    const long long oidx = ((long long)b << 16) + rem;
    const float cn = fmaf(ft, ct[oidx] - xn, xn);
    const float el = cn > 0.f ? cn : expm1f(cn);
    outp[oidx] = fmaf(ft, el - u, u);
    outp[BCN + oidx] = cn;
  }
}

extern "C" void kernel_launch(void* const* d_in, const int* in_sizes, int n_in,
                              void* d_out, int out_size, void* d_ws, size_t ws_size,
                              hipStream_t stream)
{
  (void)in_sizes; (void)n_in; (void)out_size; (void)ws_size;
  const float* x      = (const float*)d_in[0];
  const float* ct     = (const float*)d_in[1];
  const float* gdata  = (const float*)d_in[2];
  const float* emb_w  = (const float*)d_in[3];
  const float* emb_b  = (const float*)d_in[4];
  const float* emb2_w = (const float*)d_in[5];
  const float* emb2_b = (const float*)d_in[6];
  const float* att_W  = (const float*)d_in[7];
  const float* att_a  = (const float*)d_in[8];
  // d_in[9] att_GL unused: softmax(relu(GL GL^T)) > 0 everywhere -> mask is a no-op
  const float* uai_w  = (const float*)d_in[10];
  const float* uai_b  = (const float*)d_in[11];
  const float* lin1_w = (const float*)d_in[12];
  const float* lin2_w = (const float*)d_in[13];
  const float* lin2_b = (const float*)d_in[14];
  const float* ln_w   = (const float*)d_in[15];
  const float* ln_b   = (const float*)d_in[16];
  float* outp = (float*)d_out;

  float* ws = (float*)d_ws;
  long long o = 0;
  auto af = [&](long long n) { float* p = ws + o; o += (n + 63) & ~63LL; return p; };
  auto au = [&](long long n) { return (u16*)af((n + 1) / 2); };

  float* Tacc    = af(S2 * BATCH);
  float* s1      = af(BNv);
  float* s2      = af(BNv);
  float* dsum    = af(2 * NI);
  float* cs1v    = af(NI);
  float* cs2v    = af(NI);
  float* v2v     = af(NI);
  float* ccv     = af(BNv);
  float* rb2ext  = af(128);
  float* rl2ext  = af(128);
  float* w12     = af(128);
  // contiguous zero-init region: Zgl, sqv, stats(64), s2mU(16)
  float* zeroreg = af(2 * BNv + 80);
  float* Zgl     = zeroreg;
  float* sqv     = zeroreg + BNv;
  float* stats   = zeroreg + 2 * BNv;
  unsigned* s2mU = (unsigned*)(stats + 64);
  u16* emb2w_bf  = au(NN2);
  u16* h0a_bf    = au(S1 * BATCH);
  u16* h0Tb      = au(S1 * BATCH);   // [b][n][e]
  u16* hTb       = au(S1 * BATCH);   // [b][c][n]
  u16* xuaiTb    = au(S1 * BATCH);   // [b][n][c]
  u16* g1b       = au(NN2);
  u16* g2tb      = au(NN2);
  u16* G12b      = au(NN2);
  u16* Abig      = au((long long)BATCH * 128 * 2048);
  u16* stack4    = au(256 * 64);
  u16* uaiw_bf   = au(CE * CE);
  u16* attwT_bf  = au(CE * CE);
  u16* bigW      = au(BNN);  // 32 MB: gram W (att-p computed on the fly)

  hipMemsetAsync(zeroreg, 0, (2 * BNv + 80) * sizeof(float), stream);

  lap_rowsum<<<2 * NI, 256, 0, stream>>>(gdata, dsum);

  mega_prep<<<11362, 256, 0, stream>>>(
      lin1_w, lin2_w, lin2_b, uai_w, att_W, att_a,
      stack4, rb2ext, rl2ext, uaiw_bf, attwT_bf, w12,
      emb2_w, emb2w_bf, x, emb_w, emb_b, h0a_bf,
      gdata, dsum, g2tb, g1b, cs1v);

  csv2_kernel<<<NI, 256, 0, stream>>>(gdata + NN2, dsum + NI, cs1v, cs2v, v2v);

  // G12t = (g1@g2)^T = TN(A=g2t, Bt=g1)
  mgemm<64, 64, 6><<<dim3(16, 16, 1), 256, 0, stream>>>(
      g2tb, g1b, nullptr, NI, NI, NI, NI, 0, 0,
      nullptr, G12b, NI, 0, nullptr, nullptr, nullptr, nullptr, nullptr);

  // h0T[b][m][e] = emb2w @ h0a^T + emb2_b, fused s1/s2/s2max epilogue
  mgemm<64, 64, 11><<<dim3(1, 16, BATCH), 256, 0, stream>>>(
      emb2w_bf, h0a_bf, (const u16*)s2mU, NI, NI, NI, NI, 0, S1,
      s1, h0Tb, CE, S1, w12, w12 + 64, emb2_b, nullptr, s2);

  // hT[b][c][n] = attW^T @ h0T^T  (K=64, bf16)
  mgemm<64, 64, 6><<<dim3(16, 1, BATCH), 256, 0, stream>>>(
      attwT_bf, h0Tb, nullptr, CE, CE, CE, CE, 0, S1,
      nullptr, hTb, NI, S1, nullptr, nullptr, nullptr, nullptr, nullptr);

  // fused two-stage: x_att = relu((p@h)/Z) then x_uai = x_att @ uaiw^T + uai_b
  // (p on the fly; Z in-block; rowsq atomics into sqv; BM=32 -> 512 blocks = 2/CU)
  mgemm<32, 64, 13><<<dim3(1, 32, BATCH), 256, 0, stream>>>(
      hTb, hTb, uaiw_bf, NI, NI, NI, NI, 0, S1,
      nullptr, xuaiTb, CE, S1, uai_b, s1, s2, (const float*)s2mU, sqv);

  // gram/gl weights (128x128 tiles; exp epilogue; rowsums into Zgl)
  mgemm<128, 128, 3><<<dim3(8, 8, BATCH), 256, 0, stream>>>(
      xuaiTb, xuaiTb, nullptr, CE, CE, CE, CE, S1, S1,
      nullptr, bigW, NI, NN2, sqv, nullptr, nullptr, nullptr, Zgl);

  cc_kernel<<<dim3(NI / 4, BATCH), 256, 0, stream>>>(bigW, Zgl, cs2v, ccv);

  // Abig = [[L1u/Z | L1L1u],[L2u/Z | L2L2u]] bf16
  mgemm<64, 64, 4><<<dim3(16, 4, BATCH), 256, 0, stream>>>(
      stack4, xuaiTb, nullptr, CE, CE, CE, CE, 0, S1,
      nullptr, Abig, 0, (long long)128 * 2048, Zgl, nullptr, nullptr, nullptr, nullptr);

  // fused: Tacc = Abig @ [W ; G12t] + b2 (x) cc + (L2 b2) (x) v2, + LN-stats atomics
  mgemm<64, 64, 5><<<dim3(16, 2, BATCH), 256, 0, stream>>>(
      Abig, bigW, G12b, NI, 2 * NI, 2048, NI, (long long)128 * 2048, NN2,
      Tacc, nullptr, NI, S2, ccv, v2v, rb2ext, rl2ext, stats);

  ln_final_t<<<256, 256, 0, stream>>>(Tacc, stats, ln_w, ln_b, ct, xuaiTb, outp);
}